// Round 3
// baseline (916.357 us; speedup 1.0000x reference)
//
#include <hip/hip_runtime.h>
#include <hip/hip_bf16.h>

typedef short s16x8 __attribute__((ext_vector_type(8)));
typedef float f32x4 __attribute__((ext_vector_type(4)));
typedef unsigned short u16;

#define DMODEL 2048
#define NH     16
#define NKV    4
#define HD     128
#define NB     4
#define SS     2048
#define KVB    32

static __device__ __forceinline__ u16 f2bf(float f) {
  unsigned u = __builtin_bit_cast(unsigned, f);
  u += 0x7fffu + ((u >> 16) & 1u);          // RNE
  return (u16)(u >> 16);
}
static __device__ __forceinline__ float bf2f(u16 h) {
  unsigned u = ((unsigned)h) << 16;
  return __builtin_bit_cast(float, u);
}

typedef const __attribute__((address_space(1))) void* gas_p;
typedef __attribute__((address_space(3))) void* las_p;
#define GLOAD16(g, l) __builtin_amdgcn_global_load_lds((gas_p)(const void*)(g), (las_p)(void*)(l), 16, 0, 0)

// ---------------------------------------------------------------- cast: f32 -> bf16
__global__ void cast_all(const float* __restrict__ x,  const float* __restrict__ wq,
                         const float* __restrict__ wk, const float* __restrict__ wv,
                         const float* __restrict__ wo,
                         u16* __restrict__ xb, u16* __restrict__ wqkv, u16* __restrict__ wob)
{
  long gid = (long)blockIdx.x * 256 + threadIdx.x;
  long i = gid * 4;
  const float* src; u16* dst; long off;
  if (i < 16777216L)       { src = x;  dst = xb;             off = i; }
  else if (i < 20971520L)  { src = wq; dst = wqkv;           off = i - 16777216L; }
  else if (i < 22020096L)  { src = wk; dst = wqkv + 4194304; off = i - 20971520L; }
  else if (i < 23068672L)  { src = wv; dst = wqkv + 5242880; off = i - 22020096L; }
  else                     { src = wo; dst = wob;            off = i - 23068672L; }
  float4 v = *(const float4*)(src + off);
  ushort4 o;
  o.x = f2bf(v.x); o.y = f2bf(v.y); o.z = f2bf(v.z); o.w = f2bf(v.w);
  *(ushort4*)(dst + off) = o;
}

// ---------------------------------------------------------------- GEMM  C = A * B^T (unchanged)
template<int NT, int EPI>
__global__ __launch_bounds__(256) void gemm_bt(
    const u16* __restrict__ A, const u16* __restrict__ Bm, int K,
    u16* __restrict__ Oq, u16* __restrict__ Ok, u16* __restrict__ Ov, float* __restrict__ Of)
{
  __shared__ __align__(16) u16 As[128 * 32];
  __shared__ __align__(16) u16 Bs[128 * 32];
  const int tid = threadIdx.x;
  const int bx = blockIdx.x % NT;
  const int by = blockIdx.x / NT;
  const int l = tid & 63, w = tid >> 6;
  const int wr = w >> 1, wc = w & 1;
  const int lg = l >> 4, lr = l & 15;
  const int rowBase = by * 128, colBase = bx * 128;

  f32x4 acc[4][4] = {};

  const int arow = tid >> 2;
  const int acol = (tid & 3) * 8;
  const u16* gA = A  + (long)(rowBase + arow) * K + acol;
  const u16* gB = Bm + (long)(colBase + arow) * K + acol;
  const long half = (long)64 * K;

  char* ldsA = (char*)As;
  char* ldsB = (char*)Bs;

  for (int k0 = 0; k0 < K; k0 += 32) {
    GLOAD16(gA + k0,        ldsA + w * 1024);
    GLOAD16(gA + half + k0, ldsA + 4096 + w * 1024);
    GLOAD16(gB + k0,        ldsB + w * 1024);
    GLOAD16(gB + half + k0, ldsB + 4096 + w * 1024);
    __syncthreads();

    s16x8 af[4], bfr[4];
#pragma unroll
    for (int m = 0; m < 4; m++) {
      int r = wr * 64 + m * 16 + lr;
      af[m] = *(const s16x8*)&As[r * 32 + lg * 8];
    }
#pragma unroll
    for (int n = 0; n < 4; n++) {
      int r = wc * 64 + n * 16 + lr;
      bfr[n] = *(const s16x8*)&Bs[r * 32 + lg * 8];
    }
#pragma unroll
    for (int m = 0; m < 4; m++)
#pragma unroll
      for (int n = 0; n < 4; n++)
        acc[m][n] = __builtin_amdgcn_mfma_f32_16x16x32_bf16(af[m], bfr[n], acc[m][n], 0, 0, 0);
    __syncthreads();
  }

#pragma unroll
  for (int m = 0; m < 4; m++)
#pragma unroll
    for (int n = 0; n < 4; n++)
#pragma unroll
      for (int r = 0; r < 4; r++) {
        int row = rowBase + wr * 64 + m * 16 + lg * 4 + r;
        int col = colBase + wc * 64 + n * 16 + lr;
        float v = acc[m][n][r];
        if (EPI == 0) {
          int b = row >> 11, s = row & 2047;
          u16 hv = f2bf(v);
          if (col < 2048) {
            int hh = col >> 7, d = col & 127;
            Oq[(((long)(b * NH + hh)) * SS + s) * HD + d] = hv;
          } else if (col < 2560) {
            int c2 = col - 2048, kh = c2 >> 7, d = c2 & 127;
            Ok[(((long)(b * NKV + kh)) * SS + s) * HD + d] = hv;
          } else {
            int c2 = col - 2560, kh = c2 >> 7, d = c2 & 127;
            Ov[(((long)(b * NKV + kh)) * HD + d) * SS + s] = hv;   // V transposed [d][s]
          }
        } else {
          Of[(long)row * DMODEL + col] = v;
        }
      }
}

// ---------------------------------------------------------------- RoPE in-place on Qr, Kr
__global__ void rope_kernel(u16* __restrict__ Qr, u16* __restrict__ Kr)
{
  long gid = (long)blockIdx.x * 256 + threadIdx.x;
  int i = (int)(gid & 63);
  long row = gid >> 6;
  int s;
  u16* p;
  const long qrows = (long)NB * NH * SS;
  if (row < qrows) { s = (int)(row & 2047); p = Qr + row * HD; }
  else             { long r2 = row - qrows; s = (int)(r2 & 2047); p = Kr + r2 * HD; }
  float inv = exp2f(-(float)i * 0.20762050593046015f);   // log2(10000)/64
  float fr = (float)s * inv;
  float c = cosf(fr), sn = sinf(fr);
  float x1 = bf2f(p[i]), x2 = bf2f(p[i + 64]);
  p[i]      = f2bf(x1 * c + x2 * sn);
  p[i + 64] = f2bf(-x1 * sn + x2 * c);
}

// ---------------------------------------------------------------- flash attention (causal, GQA)
// grid (S/128, NH, NB); 4 waves, wave w owns q-rows [qt*128+w*32, +32).
// KVB=32 tiles, K+V double-buffered (LDS 43KB -> 3 blocks/CU), raw s_barrier +
// counted vmcnt(4) keeps prefetch alive across barriers. Defer-max rescale.
__global__ __launch_bounds__(256, 4) void attn_fwd(const u16* __restrict__ Qr, const u16* __restrict__ Kr,
                                                   const u16* __restrict__ Vt, u16* __restrict__ Y)
{
  __shared__ __align__(16) u16 Ks[2][KVB * 128];   // [kv][d] 256B rows, 8KB each
  __shared__ __align__(16) u16 Vs[2][KVB * 128];   // [d-pair][2x32kv] 128B rows, 8KB each
  __shared__ __align__(16) u16 Ps[4][32 * 40];     // per-wave P, stride 40 elem (80B)

  const int tid = threadIdx.x, l = tid & 63, w = tid >> 6;
  const int lg = l >> 4, lr = l & 15;
  const int qt = gridDim.x - 1 - blockIdx.x;       // longest blocks first
  const int h = blockIdx.y, b = blockIdx.z;
  const int kvh = h >> 2;
  const int qRow0 = qt * 128 + w * 32;
  const int qMax = qRow0 + 31;
  const int nT = 4 * qt + 4;

  const u16* Qh = Qr + (((long)(b * NH + h)) * SS + qRow0) * HD;
  const u16* Kh = Kr + ((long)(b * NKV + kvh)) * SS * HD;
  const u16* Vh = Vt + ((long)(b * NKV + kvh)) * HD * SS;
  u16* Yh = Y + ((long)b * SS) * DMODEL + h * HD;

  s16x8 qf[2][4];
#pragma unroll
  for (int m = 0; m < 2; m++)
#pragma unroll
    for (int kk = 0; kk < 4; kk++)
      qf[m][kk] = *(const s16x8*)(Qh + (long)(m * 16 + lr) * HD + kk * 32 + lg * 8);

  float mrun[2][4], lrun[2][4];
#pragma unroll
  for (int m = 0; m < 2; m++)
#pragma unroll
    for (int r = 0; r < 4; r++) { mrun[m][r] = -1e30f; lrun[m][r] = 0.f; }
  f32x4 oacc[2][8] = {};
  const float scale = 0.08838834764831845f;        // 1/sqrt(128)
  u16* pp = &Ps[w][0];

  // staging: linear LDS dest (wave base + lane*16), inverse-swizzled global src
  auto stageK = [&](int buf, int kvb) {
    char* kb = (char*)&Ks[buf][0];
#pragma unroll
    for (int i = 0; i < 2; i++) {
      int L = w * 2048 + i * 1024 + l * 16;
      int r = L >> 8;                              // kv row 0..31 (256B rows)
      int cl = (L >> 4) & 15;
      int cg = (cl & 8) | ((cl ^ r) & 7);
      GLOAD16((const char*)(Kh + (long)(kvb + r) * HD) + cg * 16, kb + w * 2048 + i * 1024);
    }
  };
  auto stageV = [&](int buf, int kvb) {
    char* vb = (char*)&Vs[buf][0];
#pragma unroll
    for (int i = 0; i < 2; i++) {
      int L = w * 2048 + i * 1024 + l * 16;
      int r2 = L >> 7;                             // d-row-pair 0..63 (128B rows)
      int cl = (L >> 4) & 7;
      int cg = (cl ^ r2) & 7;
      int d  = r2 * 2 + (cg >> 2);
      int kvo = (cg & 3) * 8;
      GLOAD16((const char*)(Vh + (long)d * SS + kvb + kvo), vb + w * 2048 + i * 1024);
    }
  };

  stageV(0, 0); stageK(0, 0);

  for (int t = 0; t < nT; t++) {
    const int cur = t & 1;
    if (t + 1 < nT) {
      stageV(cur ^ 1, (t + 1) * KVB);
      stageK(cur ^ 1, (t + 1) * KVB);
      asm volatile("s_waitcnt vmcnt(4)" ::: "memory");   // drain t's K,V; keep t+1 in flight
    } else {
      asm volatile("s_waitcnt vmcnt(0)" ::: "memory");
    }
    __builtin_amdgcn_s_barrier();                        // all waves' tile-t data visible
    asm volatile("" ::: "memory");

    if (t * KVB <= qMax) {
      const char* kb = (const char*)&Ks[cur][0];
      const char* vb = (const char*)&Vs[cur][0];
      // ---- S = Q K^T
      f32x4 sacc[2][2] = {};
#pragma unroll
      for (int kk = 0; kk < 4; kk++) {
        s16x8 kf[2];
#pragma unroll
        for (int n = 0; n < 2; n++) {
          int rr = n * 16 + lr;
          int c = kk * 4 + lg;
          int cs = (c & 8) | ((c ^ rr) & 7);
          kf[n] = *(const s16x8*)(kb + rr * 256 + cs * 16);
        }
#pragma unroll
        for (int m = 0; m < 2; m++)
#pragma unroll
          for (int n = 0; n < 2; n++)
            sacc[m][n] = __builtin_amdgcn_mfma_f32_16x16x32_bf16(qf[m][kk], kf[n], sacc[m][n], 0, 0, 0);
      }
      // ---- scale + mask + row max
      const bool full = (t * KVB + (KVB - 1) <= qRow0);
      float mx[2][4];
#pragma unroll
      for (int m = 0; m < 2; m++)
#pragma unroll
        for (int r = 0; r < 4; r++) mx[m][r] = -1e30f;
#pragma unroll
      for (int m = 0; m < 2; m++)
#pragma unroll
        for (int n = 0; n < 2; n++) {
          int col = t * KVB + n * 16 + lr;
#pragma unroll
          for (int r = 0; r < 4; r++) {
            int row = qRow0 + m * 16 + lg * 4 + r;
            float v = sacc[m][n][r] * scale;
            if (!full && col > row) v = -1e30f;
            sacc[m][n][r] = v;
            mx[m][r] = fmaxf(mx[m][r], v);
          }
        }
#pragma unroll
      for (int m = 0; m < 2; m++)
#pragma unroll
        for (int r = 0; r < 4; r++) {
          mx[m][r] = fmaxf(mx[m][r], __shfl_xor(mx[m][r], 1));
          mx[m][r] = fmaxf(mx[m][r], __shfl_xor(mx[m][r], 2));
          mx[m][r] = fmaxf(mx[m][r], __shfl_xor(mx[m][r], 4));
          mx[m][r] = fmaxf(mx[m][r], __shfl_xor(mx[m][r], 8));
        }
      // ---- defer-max (T13): only rescale when max grew by > 8
      float worst = -1e30f;
#pragma unroll
      for (int m = 0; m < 2; m++)
#pragma unroll
        for (int r = 0; r < 4; r++) worst = fmaxf(worst, mx[m][r] - mrun[m][r]);
      if (!__all(worst <= 8.0f)) {
        float sf2[2][4];
#pragma unroll
        for (int m = 0; m < 2; m++)
#pragma unroll
          for (int r = 0; r < 4; r++) {
            float mnew = fmaxf(mrun[m][r], mx[m][r]);
            sf2[m][r] = __expf(mrun[m][r] - mnew);
            mrun[m][r] = mnew;
            lrun[m][r] *= sf2[m][r];
          }
#pragma unroll
        for (int m = 0; m < 2; m++)
#pragma unroll
          for (int n = 0; n < 8; n++)
#pragma unroll
            for (int r = 0; r < 4; r++) oacc[m][n][r] *= sf2[m][r];
      }
      // ---- P = exp(S - m), store P (stride-40), row sums
      float rs[2][4] = {};
#pragma unroll
      for (int m = 0; m < 2; m++)
#pragma unroll
        for (int n = 0; n < 2; n++)
#pragma unroll
          for (int r = 0; r < 4; r++) {
            float p = __expf(sacc[m][n][r] - mrun[m][r]);
            rs[m][r] += p;
            int q = m * 16 + lg * 4 + r;
            pp[q * 40 + n * 16 + lr] = f2bf(p);
          }
#pragma unroll
      for (int m = 0; m < 2; m++)
#pragma unroll
        for (int r = 0; r < 4; r++) {
          rs[m][r] += __shfl_xor(rs[m][r], 1);
          rs[m][r] += __shfl_xor(rs[m][r], 2);
          rs[m][r] += __shfl_xor(rs[m][r], 4);
          rs[m][r] += __shfl_xor(rs[m][r], 8);
          lrun[m][r] += rs[m][r];
        }
      asm volatile("s_waitcnt lgkmcnt(0)" ::: "memory");
      __builtin_amdgcn_sched_barrier(0);
      // ---- O += P V
      s16x8 pa[2];
#pragma unroll
      for (int m = 0; m < 2; m++)
        pa[m] = *(const s16x8*)((const char*)pp + (m * 16 + lr) * 80 + lg * 16);
#pragma unroll
      for (int n = 0; n < 8; n++) {
        int rr = n * 16 + lr;
        int r2 = rr >> 1;
        int c = (rr & 1) * 4 + lg;
        int cs = (c ^ r2) & 7;
        s16x8 vf = *(const s16x8*)(vb + r2 * 128 + cs * 16);
#pragma unroll
        for (int m = 0; m < 2; m++)
          oacc[m][n] = __builtin_amdgcn_mfma_f32_16x16x32_bf16(pa[m], vf, oacc[m][n], 0, 0, 0);
      }
    }
    asm volatile("" ::: "memory");
    __builtin_amdgcn_s_barrier();                        // all reads done before next overwrite
    asm volatile("" ::: "memory");
  }

#pragma unroll
  for (int m = 0; m < 2; m++)
#pragma unroll
    for (int r = 0; r < 4; r++) lrun[m][r] = 1.f / lrun[m][r];
#pragma unroll
  for (int m = 0; m < 2; m++)
#pragma unroll
    for (int n = 0; n < 8; n++)
#pragma unroll
      for (int r = 0; r < 4; r++) {
        float v = oacc[m][n][r] * lrun[m][r];
        Yh[(long)(qRow0 + m * 16 + lg * 4 + r) * DMODEL + n * 16 + lr] = f2bf(v);
      }
}

// ---------------------------------------------------------------- launch
extern "C" void kernel_launch(void* const* d_in, const int* in_sizes, int n_in,
                              void* d_out, int out_size, void* d_ws, size_t ws_size,
                              hipStream_t stream) {
  const float* x  = (const float*)d_in[0];
  const float* wq = (const float*)d_in[1];
  const float* wk = (const float*)d_in[2];
  const float* wv = (const float*)d_in[3];
  const float* wo = (const float*)d_in[4];
  float* out = (float*)d_out;
  char* ws = (char*)d_ws;

  u16* Xb   = (u16*)ws;                    // 33,554,432 B  (aliased as Y after qkv gemm)
  u16* Wqkv = (u16*)(ws + 33554432);       // 12,582,912 B
  u16* Wob  = (u16*)(ws + 46137344);       //  8,388,608 B
  u16* Qr   = (u16*)(ws + 54525952);       // 33,554,432 B
  u16* Kr   = (u16*)(ws + 88080384);       //  8,388,608 B
  u16* Vt   = (u16*)(ws + 96468992);       //  8,388,608 B
  u16* Y    = Xb;

  cast_all<<<26624, 256, 0, stream>>>(x, wq, wk, wv, wo, Xb, Wqkv, Wob);
  gemm_bt<24, 0><<<1536, 256, 0, stream>>>(Xb, Wqkv, DMODEL, Qr, Kr, Vt, nullptr);
  rope_kernel<<<40960, 256, 0, stream>>>(Qr, Kr);
  dim3 ag(SS / 128, NH, NB);
  attn_fwd<<<ag, 256, 0, stream>>>(Qr, Kr, Vt, Y);
  gemm_bt<16, 1><<<1024, 256, 0, stream>>>(Y, Wob, DMODEL, nullptr, nullptr, nullptr, out);
}

// Round 4
// 574.546 us; speedup vs baseline: 1.5949x; 1.5949x over previous
//
#include <hip/hip_runtime.h>
#include <hip/hip_bf16.h>

typedef short s16x8 __attribute__((ext_vector_type(8)));
typedef float f32x4 __attribute__((ext_vector_type(4)));
typedef unsigned short u16;

#define DMODEL 2048
#define NH     16
#define NKV    4
#define HD     128
#define NB     4
#define SS     2048

static __device__ __forceinline__ u16 f2bf(float f) {
  unsigned u = __builtin_bit_cast(unsigned, f);
  u += 0x7fffu + ((u >> 16) & 1u);          // RNE
  return (u16)(u >> 16);
}
static __device__ __forceinline__ float bf2f(u16 h) {
  unsigned u = ((unsigned)h) << 16;
  return __builtin_bit_cast(float, u);
}

typedef const __attribute__((address_space(1))) void* gas_p;
typedef __attribute__((address_space(3))) void* las_p;
#define GLOAD16(g, l) __builtin_amdgcn_global_load_lds((gas_p)(const void*)(g), (las_p)(void*)(l), 16, 0, 0)

// ---------------------------------------------------------------- cast: f32 -> bf16
__global__ void cast_all(const float* __restrict__ x,  const float* __restrict__ wq,
                         const float* __restrict__ wk, const float* __restrict__ wv,
                         const float* __restrict__ wo,
                         u16* __restrict__ xb, u16* __restrict__ wqkv, u16* __restrict__ wob)
{
  long gid = (long)blockIdx.x * 256 + threadIdx.x;
  long i = gid * 4;
  const float* src; u16* dst; long off;
  if (i < 16777216L)       { src = x;  dst = xb;             off = i; }
  else if (i < 20971520L)  { src = wq; dst = wqkv;           off = i - 16777216L; }
  else if (i < 22020096L)  { src = wk; dst = wqkv + 4194304; off = i - 20971520L; }
  else if (i < 23068672L)  { src = wv; dst = wqkv + 5242880; off = i - 22020096L; }
  else                     { src = wo; dst = wob;            off = i - 23068672L; }
  float4 v = *(const float4*)(src + off);
  ushort4 o;
  o.x = f2bf(v.x); o.y = f2bf(v.y); o.z = f2bf(v.z); o.w = f2bf(v.w);
  *(ushort4*)(dst + off) = o;
}

// ---------------------------------------------------------------- GEMM  C = A * B^T (unchanged)
template<int NT, int EPI>
__global__ __launch_bounds__(256) void gemm_bt(
    const u16* __restrict__ A, const u16* __restrict__ Bm, int K,
    u16* __restrict__ Oq, u16* __restrict__ Ok, u16* __restrict__ Ov, float* __restrict__ Of)
{
  __shared__ __align__(16) u16 As[128 * 32];
  __shared__ __align__(16) u16 Bs[128 * 32];
  const int tid = threadIdx.x;
  const int bx = blockIdx.x % NT;
  const int by = blockIdx.x / NT;
  const int l = tid & 63, w = tid >> 6;
  const int wr = w >> 1, wc = w & 1;
  const int lg = l >> 4, lr = l & 15;
  const int rowBase = by * 128, colBase = bx * 128;

  f32x4 acc[4][4] = {};

  const int arow = tid >> 2;
  const int acol = (tid & 3) * 8;
  const u16* gA = A  + (long)(rowBase + arow) * K + acol;
  const u16* gB = Bm + (long)(colBase + arow) * K + acol;
  const long half = (long)64 * K;

  char* ldsA = (char*)As;
  char* ldsB = (char*)Bs;

  for (int k0 = 0; k0 < K; k0 += 32) {
    GLOAD16(gA + k0,        ldsA + w * 1024);
    GLOAD16(gA + half + k0, ldsA + 4096 + w * 1024);
    GLOAD16(gB + k0,        ldsB + w * 1024);
    GLOAD16(gB + half + k0, ldsB + 4096 + w * 1024);
    __syncthreads();

    s16x8 af[4], bfr[4];
#pragma unroll
    for (int m = 0; m < 4; m++) {
      int r = wr * 64 + m * 16 + lr;
      af[m] = *(const s16x8*)&As[r * 32 + lg * 8];
    }
#pragma unroll
    for (int n = 0; n < 4; n++) {
      int r = wc * 64 + n * 16 + lr;
      bfr[n] = *(const s16x8*)&Bs[r * 32 + lg * 8];
    }
#pragma unroll
    for (int m = 0; m < 4; m++)
#pragma unroll
      for (int n = 0; n < 4; n++)
        acc[m][n] = __builtin_amdgcn_mfma_f32_16x16x32_bf16(af[m], bfr[n], acc[m][n], 0, 0, 0);
    __syncthreads();
  }

#pragma unroll
  for (int m = 0; m < 4; m++)
#pragma unroll
    for (int n = 0; n < 4; n++)
#pragma unroll
      for (int r = 0; r < 4; r++) {
        int row = rowBase + wr * 64 + m * 16 + lg * 4 + r;
        int col = colBase + wc * 64 + n * 16 + lr;
        float v = acc[m][n][r];
        if (EPI == 0) {
          int b = row >> 11, s = row & 2047;
          u16 hv = f2bf(v);
          if (col < 2048) {
            int hh = col >> 7, d = col & 127;
            Oq[(((long)(b * NH + hh)) * SS + s) * HD + d] = hv;
          } else if (col < 2560) {
            int c2 = col - 2048, kh = c2 >> 7, d = c2 & 127;
            Ok[(((long)(b * NKV + kh)) * SS + s) * HD + d] = hv;
          } else {
            int c2 = col - 2560, kh = c2 >> 7, d = c2 & 127;
            Ov[(((long)(b * NKV + kh)) * HD + d) * SS + s] = hv;   // V transposed [d][s]
          }
        } else {
          Of[(long)row * DMODEL + col] = v;
        }
      }
}

// ---------------------------------------------------------------- RoPE in-place on Qr, Kr
__global__ void rope_kernel(u16* __restrict__ Qr, u16* __restrict__ Kr)
{
  long gid = (long)blockIdx.x * 256 + threadIdx.x;
  int i = (int)(gid & 63);
  long row = gid >> 6;
  int s;
  u16* p;
  const long qrows = (long)NB * NH * SS;
  if (row < qrows) { s = (int)(row & 2047); p = Qr + row * HD; }
  else             { long r2 = row - qrows; s = (int)(r2 & 2047); p = Kr + r2 * HD; }
  float inv = exp2f(-(float)i * 0.20762050593046015f);   // log2(10000)/64
  float fr = (float)s * inv;
  float c = cosf(fr), sn = sinf(fr);
  float x1 = bf2f(p[i]), x2 = bf2f(p[i + 64]);
  p[i]      = f2bf(x1 * c + x2 * sn);
  p[i + 64] = f2bf(-x1 * sn + x2 * c);
}

// ---------------------------------------------------------------- flash attention (causal, GQA)
// R2 structure, 8 waves: grid (S/256, NH, NB); wave w owns q-rows [qt*256+w*32, +32).
// KVB=64, K/V double-buffered + shared by all 8 waves; per-wave swizzled P.
// LDS = 32K(K) + 32K(V) + 32K(P) = 96KB -> 1 block/CU but 2 waves/SIMD.
__global__ __launch_bounds__(512, 2) void attn_fwd(const u16* __restrict__ Qr, const u16* __restrict__ Kr,
                                                   const u16* __restrict__ Vt, u16* __restrict__ Y)
{
  __shared__ __align__(16) u16 Ks[2][64 * 128];   // [kv][d]   16KB each
  __shared__ __align__(16) u16 Vs[2][128 * 64];   // [d][kv]   16KB each
  __shared__ __align__(16) u16 Ps[8][32 * 64];    // per-wave P^T (swizzled), 4KB each

  const int tid = threadIdx.x, l = tid & 63, w = tid >> 6;
  const int lg = l >> 4, lr = l & 15;
  const int qt = gridDim.x - 1 - blockIdx.x;      // longest blocks first
  const int h = blockIdx.y, b = blockIdx.z;
  const int kvh = h >> 2;
  const int qRow0 = qt * 256 + w * 32;
  const int qMax = qRow0 + 31;
  const int nT = 4 * qt + 4;

  const u16* Qh = Qr + (((long)(b * NH + h)) * SS + qRow0) * HD;
  const u16* Kh = Kr + ((long)(b * NKV + kvh)) * SS * HD;
  const u16* Vh = Vt + ((long)(b * NKV + kvh)) * HD * SS;
  u16* Yh = Y + ((long)b * SS) * DMODEL + h * HD;

  s16x8 qf[2][4];
#pragma unroll
  for (int m = 0; m < 2; m++)
#pragma unroll
    for (int kk = 0; kk < 4; kk++)
      qf[m][kk] = *(const s16x8*)(Qh + (long)(m * 16 + lr) * HD + kk * 32 + lg * 8);

  float mrun[2][4], lrun[2][4];
#pragma unroll
  for (int m = 0; m < 2; m++)
#pragma unroll
    for (int r = 0; r < 4; r++) { mrun[m][r] = -1e30f; lrun[m][r] = 0.f; }
  f32x4 oacc[2][8] = {};
  const float scale = 0.08838834764831845f;       // 1/sqrt(128)
  u16* pp = &Ps[w][0];

  // ---- staging: linear LDS dest, inverse-swizzled global source (m173)
  // 8 waves cooperatively stage the 16KB tile: wave w covers [w*2048, +2048) x2
  auto stageK = [&](int buf, int kvb) {
    char* kb = (char*)&Ks[buf][0];
#pragma unroll
    for (int i = 0; i < 2; i++) {
      int L = w * 2048 + i * 1024 + l * 16;       // byte this lane lands at
      int r = L >> 8;                             // kv row 0..63 (256B rows)
      int cl = (L >> 4) & 15;                     // 16B chunk in row
      int cg = (cl & 8) | ((cl ^ r) & 7);
      GLOAD16((const char*)(Kh + (long)(kvb + r) * HD) + cg * 16, kb + w * 2048 + i * 1024);
    }
  };
  auto stageV = [&](int buf, int kvb) {
    char* vb = (char*)&Vs[buf][0];
#pragma unroll
    for (int i = 0; i < 2; i++) {
      int L = w * 2048 + i * 1024 + l * 16;
      int r = L >> 7;                             // d row 0..127 (128B rows)
      int cl = (L >> 4) & 7;
      int cg = (cl ^ r) & 7;
      GLOAD16((const char*)(Vh + (long)r * SS + kvb) + cg * 16, vb + w * 2048 + i * 1024);
    }
  };

  stageK(0, 0); stageV(0, 0);
  __syncthreads();

  for (int t = 0; t < nT; t++) {
    const int cur = t & 1;
    if (t + 1 < nT) { stageK(cur ^ 1, (t + 1) * 64); stageV(cur ^ 1, (t + 1) * 64); }

    if (t * 64 <= qMax) {                          // wave has live rows in this tile
      const char* kb = (const char*)&Ks[cur][0];
      const char* vb = (const char*)&Vs[cur][0];
      // ---- S = Q K^T
      f32x4 sacc[2][4] = {};
#pragma unroll
      for (int kk = 0; kk < 4; kk++) {
        s16x8 kf[4];
#pragma unroll
        for (int n = 0; n < 4; n++) {
          int rr = n * 16 + lr;
          int ch = kk * 4 + lg;
          int chs = (ch & 8) | ((ch ^ rr) & 7);
          kf[n] = *(const s16x8*)(kb + rr * 256 + chs * 16);
        }
#pragma unroll
        for (int m = 0; m < 2; m++)
#pragma unroll
          for (int n = 0; n < 4; n++)
            sacc[m][n] = __builtin_amdgcn_mfma_f32_16x16x32_bf16(qf[m][kk], kf[n], sacc[m][n], 0, 0, 0);
      }
      // ---- scale + mask + row max
      const bool full = (t * 64 + 63 <= qRow0);
      float mx[2][4];
#pragma unroll
      for (int m = 0; m < 2; m++)
#pragma unroll
        for (int r = 0; r < 4; r++) mx[m][r] = -1e30f;
#pragma unroll
      for (int m = 0; m < 2; m++)
#pragma unroll
        for (int n = 0; n < 4; n++) {
          int col = t * 64 + n * 16 + lr;
#pragma unroll
          for (int r = 0; r < 4; r++) {
            int row = qRow0 + m * 16 + lg * 4 + r;
            float v = sacc[m][n][r] * scale;
            if (!full && col > row) v = -1e30f;
            sacc[m][n][r] = v;
            mx[m][r] = fmaxf(mx[m][r], v);
          }
        }
#pragma unroll
      for (int m = 0; m < 2; m++)
#pragma unroll
        for (int r = 0; r < 4; r++) {
          mx[m][r] = fmaxf(mx[m][r], __shfl_xor(mx[m][r], 1));
          mx[m][r] = fmaxf(mx[m][r], __shfl_xor(mx[m][r], 2));
          mx[m][r] = fmaxf(mx[m][r], __shfl_xor(mx[m][r], 4));
          mx[m][r] = fmaxf(mx[m][r], __shfl_xor(mx[m][r], 8));
        }
      float sf[2][4], rs[2][4];
#pragma unroll
      for (int m = 0; m < 2; m++)
#pragma unroll
        for (int r = 0; r < 4; r++) {
          float mnew = fmaxf(mrun[m][r], mx[m][r]);
          sf[m][r] = __expf(mrun[m][r] - mnew);
          mrun[m][r] = mnew;
          rs[m][r] = 0.f;
        }
      // ---- P = exp(S - m), store swizzled P^T, row sums
#pragma unroll
      for (int m = 0; m < 2; m++)
#pragma unroll
        for (int n = 0; n < 4; n++)
#pragma unroll
          for (int r = 0; r < 4; r++) {
            float p = __expf(sacc[m][n][r] - mrun[m][r]);
            rs[m][r] += p;
            int q = m * 16 + lg * 4 + r;
            int byte = (q * 128 + (n * 16 + lr) * 2) ^ ((q & 7) << 4);
            *(u16*)((char*)pp + byte) = f2bf(p);
          }
#pragma unroll
      for (int m = 0; m < 2; m++)
#pragma unroll
        for (int r = 0; r < 4; r++) {
          rs[m][r] += __shfl_xor(rs[m][r], 1);
          rs[m][r] += __shfl_xor(rs[m][r], 2);
          rs[m][r] += __shfl_xor(rs[m][r], 4);
          rs[m][r] += __shfl_xor(rs[m][r], 8);
          lrun[m][r] = lrun[m][r] * sf[m][r] + rs[m][r];
        }
#pragma unroll
      for (int m = 0; m < 2; m++)
#pragma unroll
        for (int n = 0; n < 8; n++)
#pragma unroll
          for (int r = 0; r < 4; r++) oacc[m][n][r] *= sf[m][r];

      asm volatile("s_waitcnt lgkmcnt(0)" ::: "memory");
      __builtin_amdgcn_sched_barrier(0);
      s16x8 pa[2][2];
#pragma unroll
      for (int m = 0; m < 2; m++)
#pragma unroll
        for (int kk = 0; kk < 2; kk++) {
          int q = m * 16 + lr;
          int chs = ((kk * 4 + lg) ^ q) & 7;
          pa[m][kk] = *(const s16x8*)((const char*)pp + q * 128 + chs * 16);
        }
      // ---- O += P V
#pragma unroll
      for (int kk = 0; kk < 2; kk++) {
        s16x8 vf[8];
#pragma unroll
        for (int n = 0; n < 8; n++) {
          int rr = n * 16 + lr;
          int chs = ((kk * 4 + lg) ^ rr) & 7;
          vf[n] = *(const s16x8*)(vb + rr * 128 + chs * 16);
        }
#pragma unroll
        for (int m = 0; m < 2; m++)
#pragma unroll
          for (int n = 0; n < 8; n++)
            oacc[m][n] = __builtin_amdgcn_mfma_f32_16x16x32_bf16(pa[m][kk], vf[n], oacc[m][n], 0, 0, 0);
      }
    }
    __syncthreads();
  }

#pragma unroll
  for (int m = 0; m < 2; m++)
#pragma unroll
    for (int r = 0; r < 4; r++) lrun[m][r] = 1.f / lrun[m][r];
#pragma unroll
  for (int m = 0; m < 2; m++)
#pragma unroll
    for (int n = 0; n < 8; n++)
#pragma unroll
      for (int r = 0; r < 4; r++) {
        float v = oacc[m][n][r] * lrun[m][r];
        Yh[(long)(qRow0 + m * 16 + lg * 4 + r) * DMODEL + n * 16 + lr] = f2bf(v);
      }
}

// ---------------------------------------------------------------- launch
extern "C" void kernel_launch(void* const* d_in, const int* in_sizes, int n_in,
                              void* d_out, int out_size, void* d_ws, size_t ws_size,
                              hipStream_t stream) {
  const float* x  = (const float*)d_in[0];
  const float* wq = (const float*)d_in[1];
  const float* wk = (const float*)d_in[2];
  const float* wv = (const float*)d_in[3];
  const float* wo = (const float*)d_in[4];
  float* out = (float*)d_out;
  char* ws = (char*)d_ws;

  u16* Xb   = (u16*)ws;                    // 33,554,432 B  (aliased as Y after qkv gemm)
  u16* Wqkv = (u16*)(ws + 33554432);       // 12,582,912 B
  u16* Wob  = (u16*)(ws + 46137344);       //  8,388,608 B
  u16* Qr   = (u16*)(ws + 54525952);       // 33,554,432 B
  u16* Kr   = (u16*)(ws + 88080384);       //  8,388,608 B
  u16* Vt   = (u16*)(ws + 96468992);       //  8,388,608 B
  u16* Y    = Xb;

  cast_all<<<26624, 256, 0, stream>>>(x, wq, wk, wv, wo, Xb, Wqkv, Wob);
  gemm_bt<24, 0><<<1536, 256, 0, stream>>>(Xb, Wqkv, DMODEL, Qr, Kr, Vt, nullptr);
  rope_kernel<<<40960, 256, 0, stream>>>(Qr, Kr);
  dim3 ag(SS / 256, NH, NB);
  attn_fwd<<<ag, 512, 0, stream>>>(Qr, Kr, Vt, Y);
  gemm_bt<16, 1><<<1024, 256, 0, stream>>>(Y, Wob, DMODEL, nullptr, nullptr, nullptr, out);
}

// Round 6
// 514.504 us; speedup vs baseline: 1.7811x; 1.1167x over previous
//
#include <hip/hip_runtime.h>
#include <hip/hip_bf16.h>

typedef short s16x8 __attribute__((ext_vector_type(8)));
typedef float f32x4 __attribute__((ext_vector_type(4)));
typedef float f32x16 __attribute__((ext_vector_type(16)));
typedef unsigned u32;
typedef unsigned u32x4 __attribute__((ext_vector_type(4)));
typedef unsigned short u16;

#define DMODEL 2048
#define NH     16
#define NKV    4
#define HD     128
#define NB     4
#define SS     2048

static __device__ __forceinline__ u16 f2bf(float f) {
  unsigned u = __builtin_bit_cast(unsigned, f);
  u += 0x7fffu + ((u >> 16) & 1u);          // RNE
  return (u16)(u >> 16);
}
static __device__ __forceinline__ float bf2f(u16 h) {
  unsigned u = ((unsigned)h) << 16;
  return __builtin_bit_cast(float, u);
}
static __device__ __forceinline__ u32 packbf(float a, float b) {
  return (u32)f2bf(a) | ((u32)f2bf(b) << 16);
}

typedef const __attribute__((address_space(1))) void* gas_p;
typedef __attribute__((address_space(3))) void* las_p;
#define GLOAD16(g, l) __builtin_amdgcn_global_load_lds((gas_p)(const void*)(g), (las_p)(void*)(l), 16, 0, 0)

// ---------------------------------------------------------------- cast: f32 -> bf16
__global__ void cast_all(const float* __restrict__ x,  const float* __restrict__ wq,
                         const float* __restrict__ wk, const float* __restrict__ wv,
                         const float* __restrict__ wo,
                         u16* __restrict__ xb, u16* __restrict__ wqkv, u16* __restrict__ wob)
{
  long gid = (long)blockIdx.x * 256 + threadIdx.x;
  long i = gid * 4;
  const float* src; u16* dst; long off;
  if (i < 16777216L)       { src = x;  dst = xb;             off = i; }
  else if (i < 20971520L)  { src = wq; dst = wqkv;           off = i - 16777216L; }
  else if (i < 22020096L)  { src = wk; dst = wqkv + 4194304; off = i - 20971520L; }
  else if (i < 23068672L)  { src = wv; dst = wqkv + 5242880; off = i - 22020096L; }
  else                     { src = wo; dst = wob;            off = i - 23068672L; }
  float4 v = *(const float4*)(src + off);
  ushort4 o;
  o.x = f2bf(v.x); o.y = f2bf(v.y); o.z = f2bf(v.z); o.w = f2bf(v.w);
  *(ushort4*)(dst + off) = o;
}

// ---------------------------------------------------------------- GEMM  C = A * B^T (unchanged)
template<int NT, int EPI>
__global__ __launch_bounds__(256) void gemm_bt(
    const u16* __restrict__ A, const u16* __restrict__ Bm, int K,
    u16* __restrict__ Oq, u16* __restrict__ Ok, u16* __restrict__ Ov, float* __restrict__ Of)
{
  __shared__ __align__(16) u16 As[128 * 32];
  __shared__ __align__(16) u16 Bs[128 * 32];
  const int tid = threadIdx.x;
  const int bx = blockIdx.x % NT;
  const int by = blockIdx.x / NT;
  const int l = tid & 63, w = tid >> 6;
  const int wr = w >> 1, wc = w & 1;
  const int lg = l >> 4, lr = l & 15;
  const int rowBase = by * 128, colBase = bx * 128;

  f32x4 acc[4][4] = {};

  const int arow = tid >> 2;
  const int acol = (tid & 3) * 8;
  const u16* gA = A  + (long)(rowBase + arow) * K + acol;
  const u16* gB = Bm + (long)(colBase + arow) * K + acol;
  const long half = (long)64 * K;

  char* ldsA = (char*)As;
  char* ldsB = (char*)Bs;

  for (int k0 = 0; k0 < K; k0 += 32) {
    GLOAD16(gA + k0,        ldsA + w * 1024);
    GLOAD16(gA + half + k0, ldsA + 4096 + w * 1024);
    GLOAD16(gB + k0,        ldsB + w * 1024);
    GLOAD16(gB + half + k0, ldsB + 4096 + w * 1024);
    __syncthreads();

    s16x8 af[4], bfr[4];
#pragma unroll
    for (int m = 0; m < 4; m++) {
      int r = wr * 64 + m * 16 + lr;
      af[m] = *(const s16x8*)&As[r * 32 + lg * 8];
    }
#pragma unroll
    for (int n = 0; n < 4; n++) {
      int r = wc * 64 + n * 16 + lr;
      bfr[n] = *(const s16x8*)&Bs[r * 32 + lg * 8];
    }
#pragma unroll
    for (int m = 0; m < 4; m++)
#pragma unroll
      for (int n = 0; n < 4; n++)
        acc[m][n] = __builtin_amdgcn_mfma_f32_16x16x32_bf16(af[m], bfr[n], acc[m][n], 0, 0, 0);
    __syncthreads();
  }

#pragma unroll
  for (int m = 0; m < 4; m++)
#pragma unroll
    for (int n = 0; n < 4; n++)
#pragma unroll
      for (int r = 0; r < 4; r++) {
        int row = rowBase + wr * 64 + m * 16 + lg * 4 + r;
        int col = colBase + wc * 64 + n * 16 + lr;
        float v = acc[m][n][r];
        if (EPI == 0) {
          int b = row >> 11, s = row & 2047;
          u16 hv = f2bf(v);
          if (col < 2048) {
            int hh = col >> 7, d = col & 127;
            Oq[(((long)(b * NH + hh)) * SS + s) * HD + d] = hv;
          } else if (col < 2560) {
            int c2 = col - 2048, kh = c2 >> 7, d = c2 & 127;
            Ok[(((long)(b * NKV + kh)) * SS + s) * HD + d] = hv;
          } else {
            int c2 = col - 2560, kh = c2 >> 7, d = c2 & 127;
            Ov[(((long)(b * NKV + kh)) * HD + d) * SS + s] = hv;   // V transposed [d][s]
          }
        } else {
          Of[(long)row * DMODEL + col] = v;
        }
      }
}

// ---------------------------------------------------------------- RoPE in-place on Qr, Kr
__global__ void rope_kernel(u16* __restrict__ Qr, u16* __restrict__ Kr)
{
  long gid = (long)blockIdx.x * 256 + threadIdx.x;
  int i = (int)(gid & 63);
  long row = gid >> 6;
  int s;
  u16* p;
  const long qrows = (long)NB * NH * SS;
  if (row < qrows) { s = (int)(row & 2047); p = Qr + row * HD; }
  else             { long r2 = row - qrows; s = (int)(r2 & 2047); p = Kr + r2 * HD; }
  float inv = exp2f(-(float)i * 0.20762050593046015f);   // log2(10000)/64
  float fr = (float)s * inv;
  float c = cosf(fr), sn = sinf(fr);
  float x1 = bf2f(p[i]), x2 = bf2f(p[i + 64]);
  p[i]      = f2bf(x1 * c + x2 * sn);
  p[i + 64] = f2bf(-x1 * sn + x2 * c);
}

// ---------------------------------------------------------------- flash attention (causal, GQA)
// 8 waves x 32 q-rows (block = 256 q). Swapped QK^T (mfma(K,Q), 32x32x16):
// lane holds the P-row of q=lane&31 (kv split across hi halves) -> softmax
// in-register (1 shfl). P -> PV A-frags via scalar bf16 pack + shfl_xor(32)
// + per-lane select (proven primitives only). K/V LDS double-buffered,
// XOR-swizzled; plain __syncthreads sync (R4-proven).
__global__ __launch_bounds__(512) void attn_fwd(const u16* __restrict__ Qr, const u16* __restrict__ Kr,
                                                const u16* __restrict__ Vt, u16* __restrict__ Y)
{
  __shared__ __align__(16) u16 Ks[2][64 * 128];   // [kv][d]  256B rows, 16KB each
  __shared__ __align__(16) u16 Vs[2][128 * 64];   // [d][kv]  128B rows, 16KB each

  const int tid = threadIdx.x, l = tid & 63, w = tid >> 6;
  const int lq = l & 31, hi = l >> 5;
  const int qt = gridDim.x - 1 - blockIdx.x;      // longest blocks first
  const int h = blockIdx.y, b = blockIdx.z;
  const int kvh = h >> 2;
  const int qRow0 = qt * 256 + w * 32;
  const int qMax = qRow0 + 31;
  const int nT = 4 * qt + 4;

  const u16* Qh = Qr + (((long)(b * NH + h)) * SS + qRow0) * HD;
  const u16* Kh = Kr + ((long)(b * NKV + kvh)) * SS * HD;
  const u16* Vh = Vt + ((long)(b * NKV + kvh)) * HD * SS;
  u16* Yh = Y + ((long)b * SS) * DMODEL + h * HD;

  // Q fragments: B-operand, col = q = lane&31, k-elems = hi*8..+7 per kk
  s16x8 qf[8];
#pragma unroll
  for (int kk = 0; kk < 8; kk++)
    qf[kk] = *(const s16x8*)(Qh + (long)lq * HD + kk * 16 + hi * 8);

  float m_run = -1e30f, l_run = 0.f;
  f32x16 oacc[4] = {};                             // row=crow(r,hi)=q, col=lane&31=d
  const float scale = 0.08838834764831845f;        // 1/sqrt(128)
  const int myq = qRow0 + lq;

  auto stageK = [&](int buf, int kvb) {
    char* kb = (char*)&Ks[buf][0];
#pragma unroll
    for (int i = 0; i < 2; i++) {
      int L = w * 2048 + i * 1024 + l * 16;
      int r = L >> 8;                              // kv row 0..63
      int cl = (L >> 4) & 15;
      int cg = (cl & 8) | ((cl ^ r) & 7);
      GLOAD16((const char*)(Kh + (long)(kvb + r) * HD) + cg * 16, kb + w * 2048 + i * 1024);
    }
  };
  auto stageV = [&](int buf, int kvb) {
    char* vb = (char*)&Vs[buf][0];
#pragma unroll
    for (int i = 0; i < 2; i++) {
      int L = w * 2048 + i * 1024 + l * 16;
      int r = L >> 7;                              // d row 0..127
      int cl = (L >> 4) & 7;
      int cg = (cl ^ r) & 7;
      GLOAD16((const char*)(Vh + (long)r * SS + kvb) + cg * 16, vb + w * 2048 + i * 1024);
    }
  };

  stageK(0, 0); stageV(0, 0);
  __syncthreads();

  for (int t = 0; t < nT; t++) {
    const int cur = t & 1;
    if (t + 1 < nT) { stageK(cur ^ 1, (t + 1) * 64); stageV(cur ^ 1, (t + 1) * 64); }

    if (t * 64 <= qMax) {
      const char* kb = (const char*)&Ks[cur][0];
      const char* vb = (const char*)&Vs[cur][0];
      // ---- S^T = K Q^T : lane holds S[kv=crow(r,hi)+tile*32][q=lane&31]
      f32x16 sacc[2] = {};
#pragma unroll
      for (int kk = 0; kk < 8; kk++) {
        int ch = kk * 2 + hi;
#pragma unroll
        for (int tile = 0; tile < 2; tile++) {
          int rr = tile * 32 + lq;
          int cs = (ch & 8) | ((ch ^ rr) & 7);
          s16x8 kf = *(const s16x8*)(kb + rr * 256 + cs * 16);
          sacc[tile] = __builtin_amdgcn_mfma_f32_32x32x16_bf16(kf, qf[kk], sacc[tile], 0, 0, 0);
        }
      }
      // ---- scale + causal mask + row max (in-lane + one half-swap)
      const bool full = (t * 64 + 63 <= qRow0);
      float pmax = -1e30f;
#pragma unroll
      for (int tile = 0; tile < 2; tile++)
#pragma unroll
        for (int r = 0; r < 16; r++) {
          int kv = t * 64 + tile * 32 + (r & 3) + 8 * (r >> 2) + 4 * hi;
          float v = sacc[tile][r] * scale;
          if (!full && kv > myq) v = -30000.f;
          sacc[tile][r] = v;
          pmax = fmaxf(pmax, v);
        }
      pmax = fmaxf(pmax, __shfl_xor(pmax, 32));
      // ---- defer-max (T13)
      if (!__all(pmax - m_run <= 8.0f)) {
        float mnew = fmaxf(m_run, pmax);
        float sf = __expf(m_run - mnew);
        m_run = mnew; l_run *= sf;
        int sfi = __builtin_bit_cast(int, sf);
#pragma unroll
        for (int r = 0; r < 16; r++) {
          int qq = (r & 3) + 8 * (r >> 2) + 4 * hi;
          float sfr = __builtin_bit_cast(float, __builtin_amdgcn_ds_bpermute(qq << 2, sfi));
#pragma unroll
          for (int n = 0; n < 4; n++) oacc[n][r] *= sfr;
        }
      }
      // ---- P = exp(S - m), row sum
      float rs = 0.f;
#pragma unroll
      for (int tile = 0; tile < 2; tile++)
#pragma unroll
        for (int r = 0; r < 16; r++) {
          float p = __expf(sacc[tile][r] - m_run);
          sacc[tile][r] = p;
          rs += p;
        }
      rs += __shfl_xor(rs, 32);
      l_run += rs;
      // ---- pack P -> PV A-frags (scalar pack + shfl_xor + select)
      s16x8 pav[4];
#pragma unroll
      for (int tile = 0; tile < 2; tile++) {
        u32 qk[8], sw[8];
#pragma unroll
        for (int j = 0; j < 8; j++) {
          qk[j] = packbf(sacc[tile][2 * j], sacc[tile][2 * j + 1]);
          sw[j] = __shfl_xor(qk[j], 32);
        }
        // frag0 (kv tile*32 + 0..15), frag1 (kv tile*32 + 16..31)
        u32x4 f0, f1;
        f0[0] = hi ? sw[2] : qk[0];
        f0[1] = hi ? sw[3] : qk[1];
        f0[2] = hi ? qk[2] : sw[0];
        f0[3] = hi ? qk[3] : sw[1];
        f1[0] = hi ? sw[6] : qk[4];
        f1[1] = hi ? sw[7] : qk[5];
        f1[2] = hi ? qk[6] : sw[4];
        f1[3] = hi ? qk[7] : sw[5];
        pav[tile * 2 + 0] = __builtin_bit_cast(s16x8, f0);
        pav[tile * 2 + 1] = __builtin_bit_cast(s16x8, f1);
      }
      // ---- O += P V   (B = V^T rows d)
#pragma unroll
      for (int n = 0; n < 4; n++) {
        int rr = n * 32 + lq;
#pragma unroll
        for (int kk = 0; kk < 4; kk++) {
          int ch = kk * 2 + hi;
          int cs = (ch ^ rr) & 7;
          s16x8 vf = *(const s16x8*)(vb + rr * 128 + cs * 16);
          oacc[n] = __builtin_amdgcn_mfma_f32_32x32x16_bf16(pav[kk], vf, oacc[n], 0, 0, 0);
        }
      }
    }
    __syncthreads();
  }

  // ---- epilogue: redistribute 1/l to output layout, store
  float linv = 1.f / l_run;
  int li = __builtin_bit_cast(int, linv);
#pragma unroll
  for (int r = 0; r < 16; r++) {
    int qq = (r & 3) + 8 * (r >> 2) + 4 * hi;
    float lr_ = __builtin_bit_cast(float, __builtin_amdgcn_ds_bpermute(qq << 2, li));
    u16* yrow = Yh + (long)(qRow0 + qq) * DMODEL;
#pragma unroll
    for (int n = 0; n < 4; n++)
      yrow[n * 32 + lq] = f2bf(oacc[n][r] * lr_);
  }
}

// ---------------------------------------------------------------- launch
extern "C" void kernel_launch(void* const* d_in, const int* in_sizes, int n_in,
                              void* d_out, int out_size, void* d_ws, size_t ws_size,
                              hipStream_t stream) {
  const float* x  = (const float*)d_in[0];
  const float* wq = (const float*)d_in[1];
  const float* wk = (const float*)d_in[2];
  const float* wv = (const float*)d_in[3];
  const float* wo = (const float*)d_in[4];
  float* out = (float*)d_out;
  char* ws = (char*)d_ws;

  u16* Xb   = (u16*)ws;                    // 33,554,432 B  (aliased as Y after qkv gemm)
  u16* Wqkv = (u16*)(ws + 33554432);       // 12,582,912 B
  u16* Wob  = (u16*)(ws + 46137344);       //  8,388,608 B
  u16* Qr   = (u16*)(ws + 54525952);       // 33,554,432 B
  u16* Kr   = (u16*)(ws + 88080384);       //  8,388,608 B
  u16* Vt   = (u16*)(ws + 96468992);       //  8,388,608 B
  u16* Y    = Xb;

  cast_all<<<26624, 256, 0, stream>>>(x, wq, wk, wv, wo, Xb, Wqkv, Wob);
  gemm_bt<24, 0><<<1536, 256, 0, stream>>>(Xb, Wqkv, DMODEL, Qr, Kr, Vt, nullptr);
  rope_kernel<<<40960, 256, 0, stream>>>(Qr, Kr);
  dim3 ag(SS / 256, NH, NB);
  attn_fwd<<<ag, 512, 0, stream>>>(Qr, Kr, Vt, Y);
  gemm_bt<16, 1><<<1024, 256, 0, stream>>>(Y, Wob, DMODEL, nullptr, nullptr, nullptr, out);
}

// Round 7
// 453.200 us; speedup vs baseline: 2.0220x; 1.1353x over previous
//
#include <hip/hip_runtime.h>
#include <hip/hip_bf16.h>

typedef short s16x8 __attribute__((ext_vector_type(8)));
typedef float f32x4 __attribute__((ext_vector_type(4)));
typedef float f32x16 __attribute__((ext_vector_type(16)));
typedef unsigned u32;
typedef unsigned u32x4 __attribute__((ext_vector_type(4)));
typedef unsigned short u16;

#define DMODEL 2048
#define NH     16
#define NKV    4
#define HD     128
#define NB     4
#define SS     2048

static __device__ __forceinline__ u16 f2bf(float f) {
  unsigned u = __builtin_bit_cast(unsigned, f);
  u += 0x7fffu + ((u >> 16) & 1u);          // RNE
  return (u16)(u >> 16);
}
static __device__ __forceinline__ float bf2f(u16 h) {
  unsigned u = ((unsigned)h) << 16;
  return __builtin_bit_cast(float, u);
}
static __device__ __forceinline__ u32 packbf(float a, float b) {
  return (u32)f2bf(a) | ((u32)f2bf(b) << 16);
}

typedef const __attribute__((address_space(1))) void* gas_p;
typedef __attribute__((address_space(3))) void* las_p;
#define GLOAD16(g, l) __builtin_amdgcn_global_load_lds((gas_p)(const void*)(g), (las_p)(void*)(l), 16, 0, 0)

// ---------------------------------------------------------------- cast: f32 -> bf16
__global__ void cast_all(const float* __restrict__ x,  const float* __restrict__ wq,
                         const float* __restrict__ wk, const float* __restrict__ wv,
                         const float* __restrict__ wo,
                         u16* __restrict__ xb, u16* __restrict__ wqkv, u16* __restrict__ wob)
{
  long gid = (long)blockIdx.x * 256 + threadIdx.x;
  long i = gid * 4;
  const float* src; u16* dst; long off;
  if (i < 16777216L)       { src = x;  dst = xb;             off = i; }
  else if (i < 20971520L)  { src = wq; dst = wqkv;           off = i - 16777216L; }
  else if (i < 22020096L)  { src = wk; dst = wqkv + 4194304; off = i - 20971520L; }
  else if (i < 23068672L)  { src = wv; dst = wqkv + 5242880; off = i - 22020096L; }
  else                     { src = wo; dst = wob;            off = i - 23068672L; }
  float4 v = *(const float4*)(src + off);
  ushort4 o;
  o.x = f2bf(v.x); o.y = f2bf(v.y); o.z = f2bf(v.z); o.w = f2bf(v.w);
  *(ushort4*)(dst + off) = o;
}

// ---------------------------------------------------------------- GEMM  C = A * B^T (unchanged)
template<int NT, int EPI>
__global__ __launch_bounds__(256) void gemm_bt(
    const u16* __restrict__ A, const u16* __restrict__ Bm, int K,
    u16* __restrict__ Oq, u16* __restrict__ Ok, u16* __restrict__ Ov, float* __restrict__ Of)
{
  __shared__ __align__(16) u16 As[128 * 32];
  __shared__ __align__(16) u16 Bs[128 * 32];
  const int tid = threadIdx.x;
  const int bx = blockIdx.x % NT;
  const int by = blockIdx.x / NT;
  const int l = tid & 63, w = tid >> 6;
  const int wr = w >> 1, wc = w & 1;
  const int lg = l >> 4, lr = l & 15;
  const int rowBase = by * 128, colBase = bx * 128;

  f32x4 acc[4][4] = {};

  const int arow = tid >> 2;
  const int acol = (tid & 3) * 8;
  const u16* gA = A  + (long)(rowBase + arow) * K + acol;
  const u16* gB = Bm + (long)(colBase + arow) * K + acol;
  const long half = (long)64 * K;

  char* ldsA = (char*)As;
  char* ldsB = (char*)Bs;

  for (int k0 = 0; k0 < K; k0 += 32) {
    GLOAD16(gA + k0,        ldsA + w * 1024);
    GLOAD16(gA + half + k0, ldsA + 4096 + w * 1024);
    GLOAD16(gB + k0,        ldsB + w * 1024);
    GLOAD16(gB + half + k0, ldsB + 4096 + w * 1024);
    __syncthreads();

    s16x8 af[4], bfr[4];
#pragma unroll
    for (int m = 0; m < 4; m++) {
      int r = wr * 64 + m * 16 + lr;
      af[m] = *(const s16x8*)&As[r * 32 + lg * 8];
    }
#pragma unroll
    for (int n = 0; n < 4; n++) {
      int r = wc * 64 + n * 16 + lr;
      bfr[n] = *(const s16x8*)&Bs[r * 32 + lg * 8];
    }
#pragma unroll
    for (int m = 0; m < 4; m++)
#pragma unroll
      for (int n = 0; n < 4; n++)
        acc[m][n] = __builtin_amdgcn_mfma_f32_16x16x32_bf16(af[m], bfr[n], acc[m][n], 0, 0, 0);
    __syncthreads();
  }

#pragma unroll
  for (int m = 0; m < 4; m++)
#pragma unroll
    for (int n = 0; n < 4; n++)
#pragma unroll
      for (int r = 0; r < 4; r++) {
        int row = rowBase + wr * 64 + m * 16 + lg * 4 + r;
        int col = colBase + wc * 64 + n * 16 + lr;
        float v = acc[m][n][r];
        if (EPI == 0) {
          int b = row >> 11, s = row & 2047;
          u16 hv = f2bf(v);
          if (col < 2048) {
            int hh = col >> 7, d = col & 127;
            Oq[(((long)(b * NH + hh)) * SS + s) * HD + d] = hv;
          } else if (col < 2560) {
            int c2 = col - 2048, kh = c2 >> 7, d = c2 & 127;
            Ok[(((long)(b * NKV + kh)) * SS + s) * HD + d] = hv;
          } else {
            int c2 = col - 2560, kh = c2 >> 7, d = c2 & 127;
            Ov[(((long)(b * NKV + kh)) * HD + d) * SS + s] = hv;   // V transposed [d][s]
          }
        } else {
          Of[(long)row * DMODEL + col] = v;
        }
      }
}

// ---------------------------------------------------------------- RoPE in-place on Qr, Kr
__global__ void rope_kernel(u16* __restrict__ Qr, u16* __restrict__ Kr)
{
  long gid = (long)blockIdx.x * 256 + threadIdx.x;
  int i = (int)(gid & 63);
  long row = gid >> 6;
  int s;
  u16* p;
  const long qrows = (long)NB * NH * SS;
  if (row < qrows) { s = (int)(row & 2047); p = Qr + row * HD; }
  else             { long r2 = row - qrows; s = (int)(r2 & 2047); p = Kr + r2 * HD; }
  float inv = exp2f(-(float)i * 0.20762050593046015f);   // log2(10000)/64
  float fr = (float)s * inv;
  float c = cosf(fr), sn = sinf(fr);
  float x1 = bf2f(p[i]), x2 = bf2f(p[i + 64]);
  p[i]      = f2bf(x1 * c + x2 * sn);
  p[i + 64] = f2bf(-x1 * sn + x2 * c);
}

// ---------------------------------------------------------------- flash attention (causal, GQA)
// Balanced pairs: block p processes qt=7-p then qt=p (each pair = 36 tile-iters).
// Grid (4, NH, NB) = 256 blocks, 1/CU, no tail. 8 waves x 32 q-rows.
// Swapped QK^T (mfma(K,Q), 32x32x16): softmax lane-local. P->PV frags via
// scalar pack + shfl_xor(32)+select. K/V LDS double-buffered, XOR-swizzled.
// Counted vmcnt(4) + raw s_barrier (R3-proven): prefetch stays in flight.
__global__ __launch_bounds__(512) void attn_fwd(const u16* __restrict__ Qr, const u16* __restrict__ Kr,
                                                const u16* __restrict__ Vt, u16* __restrict__ Y)
{
  __shared__ __align__(16) u16 Ks[2][64 * 128];   // [kv][d]  256B rows, 16KB each
  __shared__ __align__(16) u16 Vs[2][128 * 64];   // [d][kv]  128B rows, 16KB each

  const int tid = threadIdx.x, l = tid & 63, w = tid >> 6;
  const int lq = l & 31, hi = l >> 5;
  const int p = blockIdx.x, h = blockIdx.y, b = blockIdx.z;
  const int kvh = h >> 2;

  const u16* Kh = Kr + ((long)(b * NKV + kvh)) * SS * HD;
  const u16* Vh = Vt + ((long)(b * NKV + kvh)) * HD * SS;
  const float scale = 0.08838834764831845f;        // 1/sqrt(128)

  auto stageK = [&](int buf, int kvb) {
    char* kb = (char*)&Ks[buf][0];
#pragma unroll
    for (int i = 0; i < 2; i++) {
      int L = w * 2048 + i * 1024 + l * 16;
      int r = L >> 8;                              // kv row 0..63
      int cl = (L >> 4) & 15;
      int cg = (cl & 8) | ((cl ^ r) & 7);
      GLOAD16((const char*)(Kh + (long)(kvb + r) * HD) + cg * 16, kb + w * 2048 + i * 1024);
    }
  };
  auto stageV = [&](int buf, int kvb) {
    char* vb = (char*)&Vs[buf][0];
#pragma unroll
    for (int i = 0; i < 2; i++) {
      int L = w * 2048 + i * 1024 + l * 16;
      int r = L >> 7;                              // d row 0..127
      int cl = (L >> 4) & 7;
      int cg = (cl ^ r) & 7;
      GLOAD16((const char*)(Vh + (long)r * SS + kvb) + cg * 16, vb + w * 2048 + i * 1024);
    }
  };

  for (int job = 0; job < 2; job++) {
    const int qt = job ? p : 7 - p;                // big job first
    const int qRow0 = qt * 256 + w * 32;
    const int qMax = qRow0 + 31;
    const int nT = 4 * qt + 4;
    const int myq = qRow0 + lq;
    const u16* Qh = Qr + (((long)(b * NH + h)) * SS + qRow0) * HD;
    u16* Yh = Y + ((long)b * SS) * DMODEL + h * HD;

    // Q fragments: B-operand, col = q = lane&31, k-elems = hi*8..+7 per kk
    s16x8 qf[8];
#pragma unroll
    for (int kk = 0; kk < 8; kk++)
      qf[kk] = *(const s16x8*)(Qh + (long)lq * HD + kk * 16 + hi * 8);

    float m_run = -1e30f, l_run = 0.f;
    f32x16 oacc[4] = {};                           // row=crow(r,hi)=q, col=lane&31=d

    stageK(0, 0); stageV(0, 0);

    for (int t = 0; t < nT; t++) {
      const int cur = t & 1;
      if (t + 1 < nT) {
        stageK(cur ^ 1, (t + 1) * 64);
        stageV(cur ^ 1, (t + 1) * 64);
        asm volatile("s_waitcnt vmcnt(4)" ::: "memory");   // tile t landed; t+1 in flight
      } else {
        asm volatile("s_waitcnt vmcnt(0)" ::: "memory");
      }
      __builtin_amdgcn_s_barrier();
      asm volatile("" ::: "memory");

      if (t * 64 <= qMax) {
        const char* kb = (const char*)&Ks[cur][0];
        const char* vb = (const char*)&Vs[cur][0];
        // ---- S^T = K Q^T : lane holds S[kv=crow(r,hi)+tile*32][q=lane&31]
        f32x16 sacc[2] = {};
#pragma unroll
        for (int kk = 0; kk < 8; kk++) {
          int ch = kk * 2 + hi;
#pragma unroll
          for (int tile = 0; tile < 2; tile++) {
            int rr = tile * 32 + lq;
            int cs = (ch & 8) | ((ch ^ rr) & 7);
            s16x8 kf = *(const s16x8*)(kb + rr * 256 + cs * 16);
            sacc[tile] = __builtin_amdgcn_mfma_f32_32x32x16_bf16(kf, qf[kk], sacc[tile], 0, 0, 0);
          }
        }
        // ---- scale + causal mask + row max (in-lane + one half-swap)
        const bool full = (t * 64 + 63 <= qRow0);
        float pmax = -1e30f;
#pragma unroll
        for (int tile = 0; tile < 2; tile++)
#pragma unroll
          for (int r = 0; r < 16; r++) {
            int kv = t * 64 + tile * 32 + (r & 3) + 8 * (r >> 2) + 4 * hi;
            float v = sacc[tile][r] * scale;
            if (!full && kv > myq) v = -30000.f;
            sacc[tile][r] = v;
            pmax = fmaxf(pmax, v);
          }
        pmax = fmaxf(pmax, __shfl_xor(pmax, 32));
        // ---- defer-max (T13)
        if (!__all(pmax - m_run <= 8.0f)) {
          float mnew = fmaxf(m_run, pmax);
          float sf = __expf(m_run - mnew);
          m_run = mnew; l_run *= sf;
          int sfi = __builtin_bit_cast(int, sf);
#pragma unroll
          for (int r = 0; r < 16; r++) {
            int qq = (r & 3) + 8 * (r >> 2) + 4 * hi;
            float sfr = __builtin_bit_cast(float, __builtin_amdgcn_ds_bpermute(qq << 2, sfi));
#pragma unroll
            for (int n = 0; n < 4; n++) oacc[n][r] *= sfr;
          }
        }
        // ---- P = exp(S - m), row sum
        float rs = 0.f;
#pragma unroll
        for (int tile = 0; tile < 2; tile++)
#pragma unroll
          for (int r = 0; r < 16; r++) {
            float pv = __expf(sacc[tile][r] - m_run);
            sacc[tile][r] = pv;
            rs += pv;
          }
        rs += __shfl_xor(rs, 32);
        l_run += rs;
        // ---- pack P -> PV A-frags (scalar pack + shfl_xor + select)
        s16x8 pav[4];
#pragma unroll
        for (int tile = 0; tile < 2; tile++) {
          u32 qk[8], sw[8];
#pragma unroll
          for (int j = 0; j < 8; j++) {
            qk[j] = packbf(sacc[tile][2 * j], sacc[tile][2 * j + 1]);
            sw[j] = __shfl_xor(qk[j], 32);
          }
          u32x4 f0, f1;
          f0[0] = hi ? sw[2] : qk[0];
          f0[1] = hi ? sw[3] : qk[1];
          f0[2] = hi ? qk[2] : sw[0];
          f0[3] = hi ? qk[3] : sw[1];
          f1[0] = hi ? sw[6] : qk[4];
          f1[1] = hi ? sw[7] : qk[5];
          f1[2] = hi ? qk[6] : sw[4];
          f1[3] = hi ? qk[7] : sw[5];
          pav[tile * 2 + 0] = __builtin_bit_cast(s16x8, f0);
          pav[tile * 2 + 1] = __builtin_bit_cast(s16x8, f1);
        }
        // ---- O += P V   (B = V^T rows d)
#pragma unroll
        for (int n = 0; n < 4; n++) {
          int rr = n * 32 + lq;
#pragma unroll
          for (int kk = 0; kk < 4; kk++) {
            int ch = kk * 2 + hi;
            int cs = (ch ^ rr) & 7;
            s16x8 vf = *(const s16x8*)(vb + rr * 128 + cs * 16);
            oacc[n] = __builtin_amdgcn_mfma_f32_32x32x16_bf16(pav[kk], vf, oacc[n], 0, 0, 0);
          }
        }
      }
      asm volatile("" ::: "memory");
      __builtin_amdgcn_s_barrier();                // all reads done before next overwrite
      asm volatile("" ::: "memory");
    }

    // ---- epilogue: redistribute 1/l to output layout, store
    float linv = 1.f / l_run;
    int li = __builtin_bit_cast(int, linv);
#pragma unroll
    for (int r = 0; r < 16; r++) {
      int qq = (r & 3) + 8 * (r >> 2) + 4 * hi;
      float lr_ = __builtin_bit_cast(float, __builtin_amdgcn_ds_bpermute(qq << 2, li));
      u16* yrow = Yh + (long)(qRow0 + qq) * DMODEL;
#pragma unroll
      for (int n = 0; n < 4; n++)
        yrow[n * 32 + lq] = f2bf(oacc[n][r] * lr_);
    }
  }
}

// ---------------------------------------------------------------- launch
extern "C" void kernel_launch(void* const* d_in, const int* in_sizes, int n_in,
                              void* d_out, int out_size, void* d_ws, size_t ws_size,
                              hipStream_t stream) {
  const float* x  = (const float*)d_in[0];
  const float* wq = (const float*)d_in[1];
  const float* wk = (const float*)d_in[2];
  const float* wv = (const float*)d_in[3];
  const float* wo = (const float*)d_in[4];
  float* out = (float*)d_out;
  char* ws = (char*)d_ws;

  u16* Xb   = (u16*)ws;                    // 33,554,432 B  (aliased as Y after qkv gemm)
  u16* Wqkv = (u16*)(ws + 33554432);       // 12,582,912 B
  u16* Wob  = (u16*)(ws + 46137344);       //  8,388,608 B
  u16* Qr   = (u16*)(ws + 54525952);       // 33,554,432 B
  u16* Kr   = (u16*)(ws + 88080384);       //  8,388,608 B
  u16* Vt   = (u16*)(ws + 96468992);       //  8,388,608 B
  u16* Y    = Xb;

  cast_all<<<26624, 256, 0, stream>>>(x, wq, wk, wv, wo, Xb, Wqkv, Wob);
  gemm_bt<24, 0><<<1536, 256, 0, stream>>>(Xb, Wqkv, DMODEL, Qr, Kr, Vt, nullptr);
  rope_kernel<<<40960, 256, 0, stream>>>(Qr, Kr);
  dim3 ag(4, NH, NB);
  attn_fwd<<<ag, 512, 0, stream>>>(Qr, Kr, Vt, Y);
  gemm_bt<16, 1><<<1024, 256, 0, stream>>>(Y, Wob, DMODEL, nullptr, nullptr, nullptr, out);
}

// Round 8
// 378.255 us; speedup vs baseline: 2.4226x; 1.1981x over previous
//
#include <hip/hip_runtime.h>
#include <hip/hip_bf16.h>

typedef short s16x8 __attribute__((ext_vector_type(8)));
typedef float f32x4 __attribute__((ext_vector_type(4)));
typedef float f32x16 __attribute__((ext_vector_type(16)));
typedef unsigned u32;
typedef unsigned u32x4 __attribute__((ext_vector_type(4)));
typedef unsigned short u16;

#define DMODEL 2048
#define NH     16
#define NKV    4
#define HD     128
#define NB     4
#define SS     2048

static __device__ __forceinline__ u16 f2bf(float f) {
  unsigned u = __builtin_bit_cast(unsigned, f);
  u += 0x7fffu + ((u >> 16) & 1u);          // RNE
  return (u16)(u >> 16);
}
static __device__ __forceinline__ float bf2f(u16 h) {
  unsigned u = ((unsigned)h) << 16;
  return __builtin_bit_cast(float, u);
}
static __device__ __forceinline__ u32 packbf(float a, float b) {
  return (u32)f2bf(a) | ((u32)f2bf(b) << 16);
}

typedef const __attribute__((address_space(1))) void* gas_p;
typedef __attribute__((address_space(3))) void* las_p;
#define GLOAD16(g, l) __builtin_amdgcn_global_load_lds((gas_p)(const void*)(g), (las_p)(void*)(l), 16, 0, 0)

// ---------------------------------------------------------------- cast: f32 -> bf16
__global__ void cast_all(const float* __restrict__ x,  const float* __restrict__ wq,
                         const float* __restrict__ wk, const float* __restrict__ wv,
                         const float* __restrict__ wo,
                         u16* __restrict__ xb, u16* __restrict__ wqkv, u16* __restrict__ wob)
{
  long gid = (long)blockIdx.x * 256 + threadIdx.x;
  long i = gid * 4;
  const float* src; u16* dst; long off;
  if (i < 16777216L)       { src = x;  dst = xb;             off = i; }
  else if (i < 20971520L)  { src = wq; dst = wqkv;           off = i - 16777216L; }
  else if (i < 22020096L)  { src = wk; dst = wqkv + 4194304; off = i - 20971520L; }
  else if (i < 23068672L)  { src = wv; dst = wqkv + 5242880; off = i - 22020096L; }
  else                     { src = wo; dst = wob;            off = i - 23068672L; }
  float4 v = *(const float4*)(src + off);
  ushort4 o;
  o.x = f2bf(v.x); o.y = f2bf(v.y); o.z = f2bf(v.z); o.w = f2bf(v.w);
  *(ushort4*)(dst + off) = o;
}

// ---------------------------------------------------------------- GEMM  C = A * B^T
// 256x256 tile, BK=64, 512 thr = 8 waves (2M x 4N); per wave 128x64 out = 8x4
// frags, 64 MFMA / K-tile. A/B tiles in LDS with 128B rows + XOR chunk swizzle
// (write-inverse on global src, XOR on read — attn-proven). Double-buffered,
// counted vmcnt(8) + raw s_barrier. Bijective XCD swizzle on block id.
// EPI 0: scatter Q/K/V (V transposed); EPI 1: f32 row-major out.
template<int NT, int EPI>
__global__ __launch_bounds__(512) void gemm256(
    const u16* __restrict__ A, const u16* __restrict__ Bm, int K,
    u16* __restrict__ Oq, u16* __restrict__ Ok, u16* __restrict__ Ov, float* __restrict__ Of)
{
  __shared__ __align__(16) u16 lds[2][32768];     // 2 x 64KB: A h0|A h1|B h0|B h1 (16KB each)
  const int tid = threadIdx.x, l = tid & 63, w = tid >> 6;
  const int lg = l >> 4, lr = l & 15;
  const int wm = w >> 2, wn = w & 3;

  const int nwg = NT * 32;                        // grid size (M/256 = 32 rows of tiles)
  const int cpx = nwg >> 3;
  const int bid = blockIdx.x;
  const int swz = (bid & 7) * cpx + (bid >> 3);   // bijective: nwg % 8 == 0
  const int by = swz / NT, bx = swz % NT;
  const int rowBase = by * 256, colBase = bx * 256;

  // staging geometry: seg 0..7 covers 8KB each; lane lands at seg*8192 + w*1024 + l*16
  const int rloc = w * 8 + (l >> 3);              // row 0..63 within 64-row stripe
  const int cgo  = ((l & 7) ^ (l >> 3)) * 8;      // inverse-swizzled k-chunk (elems)
  const u16* gp[8];
#pragma unroll
  for (int seg = 0; seg < 8; seg++) {
    int half = (seg >> 1) & 1;
    int row  = (seg & 1) * 64 + rloc;
    if (seg < 4) gp[seg] = A  + (long)(rowBase + half * 128 + row) * K + cgo;
    else         gp[seg] = Bm + (long)(colBase + half * 128 + row) * K + cgo;
  }

  f32x4 acc[8][4] = {};

  auto stage = [&](int buf) {
    char* base = (char*)&lds[buf][0];
#pragma unroll
    for (int seg = 0; seg < 8; seg++)
      GLOAD16(gp[seg], base + seg * 8192 + w * 1024);
  };

  const int NKT = K >> 6;                          // K-tiles of 64
  stage(0);
#pragma unroll
  for (int seg = 0; seg < 8; seg++) gp[seg] += 64;
  asm volatile("s_waitcnt vmcnt(0)" ::: "memory");
  __builtin_amdgcn_s_barrier();

  for (int kt = 0; kt < NKT; kt++) {
    const int cur = kt & 1;
    if (kt + 1 < NKT) {
      stage(cur ^ 1);
#pragma unroll
      for (int seg = 0; seg < 8; seg++) gp[seg] += 64;
      asm volatile("s_waitcnt vmcnt(8)" ::: "memory");   // tile kt landed; kt+1 in flight
    } else {
      asm volatile("s_waitcnt vmcnt(0)" ::: "memory");
    }
    __builtin_amdgcn_s_barrier();
    asm volatile("" ::: "memory");

    const char* ab = (const char*)&lds[cur][0] + wm * 16384;
    const char* bb = (const char*)&lds[cur][0] + 32768 + (wn >> 1) * 16384;
    const int rbB = (wn & 1) * 64;
#pragma unroll
    for (int ks = 0; ks < 2; ks++) {
      const int c = ks * 4 + lg;
      s16x8 af[8], bfr[4];
#pragma unroll
      for (int m = 0; m < 8; m++) {
        int rr = m * 16 + lr;
        af[m] = *(const s16x8*)(ab + rr * 128 + ((c ^ (rr & 7)) * 16));
      }
#pragma unroll
      for (int n = 0; n < 4; n++) {
        int rb = rbB + n * 16 + lr;
        bfr[n] = *(const s16x8*)(bb + rb * 128 + ((c ^ (rb & 7)) * 16));
      }
      __builtin_amdgcn_s_setprio(1);
#pragma unroll
      for (int m = 0; m < 8; m++)
#pragma unroll
        for (int n = 0; n < 4; n++)
          acc[m][n] = __builtin_amdgcn_mfma_f32_16x16x32_bf16(af[m], bfr[n], acc[m][n], 0, 0, 0);
      __builtin_amdgcn_s_setprio(0);
    }
    asm volatile("" ::: "memory");
    __builtin_amdgcn_s_barrier();                  // reads done before buffer overwrite
    asm volatile("" ::: "memory");
  }

#pragma unroll
  for (int m = 0; m < 8; m++)
#pragma unroll
    for (int n = 0; n < 4; n++)
#pragma unroll
      for (int r = 0; r < 4; r++) {
        int row = rowBase + wm * 128 + m * 16 + lg * 4 + r;
        int col = colBase + wn * 64 + n * 16 + lr;
        float v = acc[m][n][r];
        if (EPI == 0) {
          int b = row >> 11, s = row & 2047;
          u16 hv = f2bf(v);
          if (col < 2048) {
            int hh = col >> 7, d = col & 127;
            Oq[(((long)(b * NH + hh)) * SS + s) * HD + d] = hv;
          } else if (col < 2560) {
            int c2 = col - 2048, kh = c2 >> 7, d = c2 & 127;
            Ok[(((long)(b * NKV + kh)) * SS + s) * HD + d] = hv;
          } else {
            int c2 = col - 2560, kh = c2 >> 7, d = c2 & 127;
            Ov[(((long)(b * NKV + kh)) * HD + d) * SS + s] = hv;   // V transposed [d][s]
          }
        } else {
          Of[(long)row * DMODEL + col] = v;
        }
      }
}

// ---------------------------------------------------------------- RoPE in-place on Qr, Kr
__global__ void rope_kernel(u16* __restrict__ Qr, u16* __restrict__ Kr)
{
  long gid = (long)blockIdx.x * 256 + threadIdx.x;
  int i = (int)(gid & 63);
  long row = gid >> 6;
  int s;
  u16* p;
  const long qrows = (long)NB * NH * SS;
  if (row < qrows) { s = (int)(row & 2047); p = Qr + row * HD; }
  else             { long r2 = row - qrows; s = (int)(r2 & 2047); p = Kr + r2 * HD; }
  float inv = exp2f(-(float)i * 0.20762050593046015f);   // log2(10000)/64
  float fr = (float)s * inv;
  float c = cosf(fr), sn = sinf(fr);
  float x1 = bf2f(p[i]), x2 = bf2f(p[i + 64]);
  p[i]      = f2bf(x1 * c + x2 * sn);
  p[i + 64] = f2bf(-x1 * sn + x2 * c);
}

// ---------------------------------------------------------------- flash attention (causal, GQA) — unchanged from R7
__global__ __launch_bounds__(512) void attn_fwd(const u16* __restrict__ Qr, const u16* __restrict__ Kr,
                                                const u16* __restrict__ Vt, u16* __restrict__ Y)
{
  __shared__ __align__(16) u16 Ks[2][64 * 128];   // [kv][d]  256B rows, 16KB each
  __shared__ __align__(16) u16 Vs[2][128 * 64];   // [d][kv]  128B rows, 16KB each

  const int tid = threadIdx.x, l = tid & 63, w = tid >> 6;
  const int lq = l & 31, hi = l >> 5;
  const int p = blockIdx.x, h = blockIdx.y, b = blockIdx.z;
  const int kvh = h >> 2;

  const u16* Kh = Kr + ((long)(b * NKV + kvh)) * SS * HD;
  const u16* Vh = Vt + ((long)(b * NKV + kvh)) * HD * SS;
  const float scale = 0.08838834764831845f;        // 1/sqrt(128)

  auto stageK = [&](int buf, int kvb) {
    char* kb = (char*)&Ks[buf][0];
#pragma unroll
    for (int i = 0; i < 2; i++) {
      int L = w * 2048 + i * 1024 + l * 16;
      int r = L >> 8;                              // kv row 0..63
      int cl = (L >> 4) & 15;
      int cg = (cl & 8) | ((cl ^ r) & 7);
      GLOAD16((const char*)(Kh + (long)(kvb + r) * HD) + cg * 16, kb + w * 2048 + i * 1024);
    }
  };
  auto stageV = [&](int buf, int kvb) {
    char* vb = (char*)&Vs[buf][0];
#pragma unroll
    for (int i = 0; i < 2; i++) {
      int L = w * 2048 + i * 1024 + l * 16;
      int r = L >> 7;                              // d row 0..127
      int cl = (L >> 4) & 7;
      int cg = (cl ^ r) & 7;
      GLOAD16((const char*)(Vh + (long)r * SS + kvb) + cg * 16, vb + w * 2048 + i * 1024);
    }
  };

  for (int job = 0; job < 2; job++) {
    const int qt = job ? p : 7 - p;                // big job first
    const int qRow0 = qt * 256 + w * 32;
    const int qMax = qRow0 + 31;
    const int nT = 4 * qt + 4;
    const int myq = qRow0 + lq;
    const u16* Qh = Qr + (((long)(b * NH + h)) * SS + qRow0) * HD;
    u16* Yh = Y + ((long)b * SS) * DMODEL + h * HD;

    s16x8 qf[8];
#pragma unroll
    for (int kk = 0; kk < 8; kk++)
      qf[kk] = *(const s16x8*)(Qh + (long)lq * HD + kk * 16 + hi * 8);

    float m_run = -1e30f, l_run = 0.f;
    f32x16 oacc[4] = {};                           // row=crow(r,hi)=q, col=lane&31=d

    stageK(0, 0); stageV(0, 0);

    for (int t = 0; t < nT; t++) {
      const int cur = t & 1;
      if (t + 1 < nT) {
        stageK(cur ^ 1, (t + 1) * 64);
        stageV(cur ^ 1, (t + 1) * 64);
        asm volatile("s_waitcnt vmcnt(4)" ::: "memory");   // tile t landed; t+1 in flight
      } else {
        asm volatile("s_waitcnt vmcnt(0)" ::: "memory");
      }
      __builtin_amdgcn_s_barrier();
      asm volatile("" ::: "memory");

      if (t * 64 <= qMax) {
        const char* kb = (const char*)&Ks[cur][0];
        const char* vb = (const char*)&Vs[cur][0];
        f32x16 sacc[2] = {};
#pragma unroll
        for (int kk = 0; kk < 8; kk++) {
          int ch = kk * 2 + hi;
#pragma unroll
          for (int tile = 0; tile < 2; tile++) {
            int rr = tile * 32 + lq;
            int cs = (ch & 8) | ((ch ^ rr) & 7);
            s16x8 kf = *(const s16x8*)(kb + rr * 256 + cs * 16);
            sacc[tile] = __builtin_amdgcn_mfma_f32_32x32x16_bf16(kf, qf[kk], sacc[tile], 0, 0, 0);
          }
        }
        const bool full = (t * 64 + 63 <= qRow0);
        float pmax = -1e30f;
#pragma unroll
        for (int tile = 0; tile < 2; tile++)
#pragma unroll
          for (int r = 0; r < 16; r++) {
            int kv = t * 64 + tile * 32 + (r & 3) + 8 * (r >> 2) + 4 * hi;
            float v = sacc[tile][r] * scale;
            if (!full && kv > myq) v = -30000.f;
            sacc[tile][r] = v;
            pmax = fmaxf(pmax, v);
          }
        pmax = fmaxf(pmax, __shfl_xor(pmax, 32));
        if (!__all(pmax - m_run <= 8.0f)) {
          float mnew = fmaxf(m_run, pmax);
          float sf = __expf(m_run - mnew);
          m_run = mnew; l_run *= sf;
          int sfi = __builtin_bit_cast(int, sf);
#pragma unroll
          for (int r = 0; r < 16; r++) {
            int qq = (r & 3) + 8 * (r >> 2) + 4 * hi;
            float sfr = __builtin_bit_cast(float, __builtin_amdgcn_ds_bpermute(qq << 2, sfi));
#pragma unroll
            for (int n = 0; n < 4; n++) oacc[n][r] *= sfr;
          }
        }
        float rs = 0.f;
#pragma unroll
        for (int tile = 0; tile < 2; tile++)
#pragma unroll
          for (int r = 0; r < 16; r++) {
            float pv = __expf(sacc[tile][r] - m_run);
            sacc[tile][r] = pv;
            rs += pv;
          }
        rs += __shfl_xor(rs, 32);
        l_run += rs;
        s16x8 pav[4];
#pragma unroll
        for (int tile = 0; tile < 2; tile++) {
          u32 qk[8], sw[8];
#pragma unroll
          for (int j = 0; j < 8; j++) {
            qk[j] = packbf(sacc[tile][2 * j], sacc[tile][2 * j + 1]);
            sw[j] = __shfl_xor(qk[j], 32);
          }
          u32x4 f0, f1;
          f0[0] = hi ? sw[2] : qk[0];
          f0[1] = hi ? sw[3] : qk[1];
          f0[2] = hi ? qk[2] : sw[0];
          f0[3] = hi ? qk[3] : sw[1];
          f1[0] = hi ? sw[6] : qk[4];
          f1[1] = hi ? sw[7] : qk[5];
          f1[2] = hi ? qk[6] : sw[4];
          f1[3] = hi ? qk[7] : sw[5];
          pav[tile * 2 + 0] = __builtin_bit_cast(s16x8, f0);
          pav[tile * 2 + 1] = __builtin_bit_cast(s16x8, f1);
        }
#pragma unroll
        for (int n = 0; n < 4; n++) {
          int rr = n * 32 + lq;
#pragma unroll
          for (int kk = 0; kk < 4; kk++) {
            int ch = kk * 2 + hi;
            int cs = (ch ^ rr) & 7;
            s16x8 vf = *(const s16x8*)(vb + rr * 128 + cs * 16);
            oacc[n] = __builtin_amdgcn_mfma_f32_32x32x16_bf16(pav[kk], vf, oacc[n], 0, 0, 0);
          }
        }
      }
      asm volatile("" ::: "memory");
      __builtin_amdgcn_s_barrier();                // all reads done before next overwrite
      asm volatile("" ::: "memory");
    }

    float linv = 1.f / l_run;
    int li = __builtin_bit_cast(int, linv);
#pragma unroll
    for (int r = 0; r < 16; r++) {
      int qq = (r & 3) + 8 * (r >> 2) + 4 * hi;
      float lr_ = __builtin_bit_cast(float, __builtin_amdgcn_ds_bpermute(qq << 2, li));
      u16* yrow = Yh + (long)(qRow0 + qq) * DMODEL;
#pragma unroll
      for (int n = 0; n < 4; n++)
        yrow[n * 32 + lq] = f2bf(oacc[n][r] * lr_);
    }
  }
}

// ---------------------------------------------------------------- launch
extern "C" void kernel_launch(void* const* d_in, const int* in_sizes, int n_in,
                              void* d_out, int out_size, void* d_ws, size_t ws_size,
                              hipStream_t stream) {
  const float* x  = (const float*)d_in[0];
  const float* wq = (const float*)d_in[1];
  const float* wk = (const float*)d_in[2];
  const float* wv = (const float*)d_in[3];
  const float* wo = (const float*)d_in[4];
  float* out = (float*)d_out;
  char* ws = (char*)d_ws;

  u16* Xb   = (u16*)ws;                    // 33,554,432 B  (aliased as Y after qkv gemm)
  u16* Wqkv = (u16*)(ws + 33554432);       // 12,582,912 B
  u16* Wob  = (u16*)(ws + 46137344);       //  8,388,608 B
  u16* Qr   = (u16*)(ws + 54525952);       // 33,554,432 B
  u16* Kr   = (u16*)(ws + 88080384);       //  8,388,608 B
  u16* Vt   = (u16*)(ws + 96468992);       //  8,388,608 B
  u16* Y    = Xb;

  cast_all<<<26624, 256, 0, stream>>>(x, wq, wk, wv, wo, Xb, Wqkv, Wob);
  gemm256<12, 0><<<384, 512, 0, stream>>>(Xb, Wqkv, DMODEL, Qr, Kr, Vt, nullptr);
  rope_kernel<<<40960, 256, 0, stream>>>(Qr, Kr);
  dim3 ag(4, NH, NB);
  attn_fwd<<<ag, 512, 0, stream>>>(Qr, Kr, Vt, Y);
  gemm256<8, 1><<<256, 512, 0, stream>>>(Y, Wob, DMODEL, nullptr, nullptr, nullptr, out);
}

// Round 9
// 370.523 us; speedup vs baseline: 2.4731x; 1.0209x over previous
//
#include <hip/hip_runtime.h>
#include <hip/hip_bf16.h>

typedef short s16x8 __attribute__((ext_vector_type(8)));
typedef float f32x4 __attribute__((ext_vector_type(4)));
typedef float f32x16 __attribute__((ext_vector_type(16)));
typedef unsigned u32;
typedef unsigned u32x4 __attribute__((ext_vector_type(4)));
typedef unsigned short u16;

#define DMODEL 2048
#define NH     16
#define NKV    4
#define HD     128
#define NB     4
#define SS     2048

static __device__ __forceinline__ u16 f2bf(float f) {
  unsigned u = __builtin_bit_cast(unsigned, f);
  u += 0x7fffu + ((u >> 16) & 1u);          // RNE
  return (u16)(u >> 16);
}
static __device__ __forceinline__ float bf2f(u16 h) {
  unsigned u = ((unsigned)h) << 16;
  return __builtin_bit_cast(float, u);
}
static __device__ __forceinline__ u32 packbf(float a, float b) {
  return (u32)f2bf(a) | ((u32)f2bf(b) << 16);
}

typedef const __attribute__((address_space(1))) void* gas_p;
typedef __attribute__((address_space(3))) void* las_p;
#define GLOAD16(g, l) __builtin_amdgcn_global_load_lds((gas_p)(const void*)(g), (las_p)(void*)(l), 16, 0, 0)

// ---------------------------------------------------------------- cast: f32 -> bf16
__global__ void cast_all(const float* __restrict__ x,  const float* __restrict__ wq,
                         const float* __restrict__ wk, const float* __restrict__ wv,
                         const float* __restrict__ wo,
                         u16* __restrict__ xb, u16* __restrict__ wqkv, u16* __restrict__ wob)
{
  long gid = (long)blockIdx.x * 256 + threadIdx.x;
  long i = gid * 4;
  const float* src; u16* dst; long off;
  if (i < 16777216L)       { src = x;  dst = xb;             off = i; }
  else if (i < 20971520L)  { src = wq; dst = wqkv;           off = i - 16777216L; }
  else if (i < 22020096L)  { src = wk; dst = wqkv + 4194304; off = i - 20971520L; }
  else if (i < 23068672L)  { src = wv; dst = wqkv + 5242880; off = i - 22020096L; }
  else                     { src = wo; dst = wob;            off = i - 23068672L; }
  float4 v = *(const float4*)(src + off);
  ushort4 o;
  o.x = f2bf(v.x); o.y = f2bf(v.y); o.z = f2bf(v.z); o.w = f2bf(v.w);
  *(ushort4*)(dst + off) = o;
}

// ---------------------------------------------------------------- GEMM  C = A * B^T
// 256x256 tile, BK=64, 8 waves (2M x 4N). 4-phase/K-tile schedule:
// each phase {ds_read subtile || stage 1/4 of next tile || 16 MFMA}, 2 barriers
// per phase, derived counted waits: vmcnt(4)@P2, vmcnt(2)@P4 (see R9 notes).
// XOR chunk swizzle on LDS rows (conflict-free, R8-verified). XCD swizzle.
// EPI 0: scatter Q/K/V (V transposed); EPI 1: f32 row-major out.
#define GPHASE(MQ, STG, WAIT)                                               \
  {                                                                         \
    s16x8 af[2][2];                                                         \
    _Pragma("unroll") for (int j = 0; j < 2; j++)                           \
      _Pragma("unroll") for (int ks = 0; ks < 2; ks++) {                    \
        int rr = (MQ) * 32 + j * 16 + lr;                                   \
        int c = ks * 4 + lg;                                                \
        af[j][ks] = *(const s16x8*)(ab + rr * 128 + ((c ^ (rr & 7)) * 16)); \
      }                                                                     \
    STG;                                                                    \
    WAIT;                                                                   \
    asm volatile("" ::: "memory");                                          \
    __builtin_amdgcn_s_barrier();                                           \
    asm volatile("" ::: "memory");                                          \
    __builtin_amdgcn_s_setprio(1);                                          \
    _Pragma("unroll") for (int ks = 0; ks < 2; ks++)                        \
      _Pragma("unroll") for (int j = 0; j < 2; j++)                         \
        _Pragma("unroll") for (int n = 0; n < 4; n++)                       \
          acc[(MQ) * 2 + j][n] = __builtin_amdgcn_mfma_f32_16x16x32_bf16(   \
              af[j][ks], bfr[n][ks], acc[(MQ) * 2 + j][n], 0, 0, 0);        \
    __builtin_amdgcn_s_setprio(0);                                          \
    asm volatile("" ::: "memory");                                          \
    __builtin_amdgcn_s_barrier();                                           \
    asm volatile("" ::: "memory");                                          \
  }

template<int NT, int EPI>
__global__ __launch_bounds__(512) void gemm256(
    const u16* __restrict__ A, const u16* __restrict__ Bm, int K,
    u16* __restrict__ Oq, u16* __restrict__ Ok, u16* __restrict__ Ov, float* __restrict__ Of)
{
  __shared__ __align__(16) u16 lds[2][32768];     // 2 x 64KB: A[256 rows]|B[256 rows], 128B rows
  const int tid = threadIdx.x, l = tid & 63, w = tid >> 6;
  const int lg = l >> 4, lr = l & 15;
  const int wm = w >> 2, wn = w & 3;

  const int nwg = NT * 32;
  const int cpx = nwg >> 3;
  const int bid = blockIdx.x;
  const int swz = (bid & 7) * cpx + (bid >> 3);   // bijective: nwg % 8 == 0
  const int by = swz / NT, bx = swz % NT;
  const int rowBase = by * 256, colBase = bx * 256;

  // staging geometry: seg s = 8KB = 64 rows; lane covers seg*8192 + w*1024 + l*16
  const int rloc = w * 8 + (l >> 3);              // row 0..63 within seg
  const int cgo  = ((l & 7) ^ (l >> 3)) * 8;      // inverse-swizzled k-chunk (elems)
  const u16* gp[8];
#pragma unroll
  for (int seg = 0; seg < 8; seg++) {
    int half = (seg >> 1) & 1;
    int row  = (seg & 1) * 64 + rloc;
    if (seg < 4) gp[seg] = A  + (long)(rowBase + half * 128 + row) * K + cgo;
    else         gp[seg] = Bm + (long)(colBase + half * 128 + row) * K + cgo;
  }

  f32x4 acc[8][4] = {};

  const int NKT = K >> 6;
  {   // prologue: stage tile 0 fully, drain
    char* nb = (char*)&lds[0][0];
#pragma unroll
    for (int seg = 0; seg < 8; seg++)
      GLOAD16(gp[seg], nb + seg * 8192 + w * 1024);
#pragma unroll
    for (int seg = 0; seg < 8; seg++) gp[seg] += 64;
    asm volatile("s_waitcnt vmcnt(0)" ::: "memory");
    __builtin_amdgcn_s_barrier();
    asm volatile("" ::: "memory");
  }

  for (int kt = 0; kt < NKT; kt++) {
    const int cur = kt & 1;
    const bool pre = (kt + 1 < NKT);
    const char* ab = (const char*)&lds[cur][0] + wm * 16384;
    const char* bb = (const char*)&lds[cur][0] + 32768 + (wn >> 1) * 16384;
    char* nb = (char*)&lds[cur ^ 1][0];
    const int rbB = (wn & 1) * 64;

    // ---- P1: read all B-frags + A m0,m1; stage B segs 4,5
    s16x8 bfr[4][2];
#pragma unroll
    for (int n = 0; n < 4; n++)
#pragma unroll
      for (int ks = 0; ks < 2; ks++) {
        int rb = rbB + n * 16 + lr;
        int c = ks * 4 + lg;
        bfr[n][ks] = *(const s16x8*)(bb + rb * 128 + ((c ^ (rb & 7)) * 16));
      }
    GPHASE(0,
      { if (pre) { GLOAD16(gp[4], nb + 4 * 8192 + w * 1024);
                   GLOAD16(gp[5], nb + 5 * 8192 + w * 1024); } },
      { });
    // ---- P2: A m2,m3; stage B segs 6,7; vmcnt(4) (guards this tile's A rows 64-127)
    GPHASE(1,
      { if (pre) { GLOAD16(gp[6], nb + 6 * 8192 + w * 1024);
                   GLOAD16(gp[7], nb + 7 * 8192 + w * 1024); } },
      { if (pre) { asm volatile("s_waitcnt vmcnt(4)" ::: "memory"); }
        else     { asm volatile("s_waitcnt vmcnt(0)" ::: "memory"); } });
    // ---- P3: A m4,m5; stage A segs 0,2
    GPHASE(2,
      { if (pre) { GLOAD16(gp[0], nb + 0 * 8192 + w * 1024);
                   GLOAD16(gp[2], nb + 2 * 8192 + w * 1024); } },
      { });
    // ---- P4: A m6,m7; stage A segs 1,3; vmcnt(2) (guards next tile's B + A rows 0-63)
    GPHASE(3,
      { if (pre) { GLOAD16(gp[1], nb + 1 * 8192 + w * 1024);
                   GLOAD16(gp[3], nb + 3 * 8192 + w * 1024); } },
      { if (pre) { asm volatile("s_waitcnt vmcnt(2)" ::: "memory"); } });

    if (pre) {
#pragma unroll
      for (int seg = 0; seg < 8; seg++) gp[seg] += 64;
    }
  }

#pragma unroll
  for (int m = 0; m < 8; m++)
#pragma unroll
    for (int n = 0; n < 4; n++)
#pragma unroll
      for (int r = 0; r < 4; r++) {
        int row = rowBase + wm * 128 + m * 16 + lg * 4 + r;
        int col = colBase + wn * 64 + n * 16 + lr;
        float v = acc[m][n][r];
        if (EPI == 0) {
          int b = row >> 11, s = row & 2047;
          u16 hv = f2bf(v);
          if (col < 2048) {
            int hh = col >> 7, d = col & 127;
            Oq[(((long)(b * NH + hh)) * SS + s) * HD + d] = hv;
          } else if (col < 2560) {
            int c2 = col - 2048, kh = c2 >> 7, d = c2 & 127;
            Ok[(((long)(b * NKV + kh)) * SS + s) * HD + d] = hv;
          } else {
            int c2 = col - 2560, kh = c2 >> 7, d = c2 & 127;
            Ov[(((long)(b * NKV + kh)) * HD + d) * SS + s] = hv;   // V transposed [d][s]
          }
        } else {
          Of[(long)row * DMODEL + col] = v;
        }
      }
}

// ---------------------------------------------------------------- RoPE in-place on Qr, Kr
__global__ void rope_kernel(u16* __restrict__ Qr, u16* __restrict__ Kr)
{
  long gid = (long)blockIdx.x * 256 + threadIdx.x;
  int i = (int)(gid & 63);
  long row = gid >> 6;
  int s;
  u16* p;
  const long qrows = (long)NB * NH * SS;
  if (row < qrows) { s = (int)(row & 2047); p = Qr + row * HD; }
  else             { long r2 = row - qrows; s = (int)(r2 & 2047); p = Kr + r2 * HD; }
  float inv = exp2f(-(float)i * 0.20762050593046015f);   // log2(10000)/64
  float fr = (float)s * inv;
  float c = cosf(fr), sn = sinf(fr);
  float x1 = bf2f(p[i]), x2 = bf2f(p[i + 64]);
  p[i]      = f2bf(x1 * c + x2 * sn);
  p[i + 64] = f2bf(-x1 * sn + x2 * c);
}

// ---------------------------------------------------------------- flash attention (causal, GQA) — unchanged from R7
__global__ __launch_bounds__(512) void attn_fwd(const u16* __restrict__ Qr, const u16* __restrict__ Kr,
                                                const u16* __restrict__ Vt, u16* __restrict__ Y)
{
  __shared__ __align__(16) u16 Ks[2][64 * 128];   // [kv][d]  256B rows, 16KB each
  __shared__ __align__(16) u16 Vs[2][128 * 64];   // [d][kv]  128B rows, 16KB each

  const int tid = threadIdx.x, l = tid & 63, w = tid >> 6;
  const int lq = l & 31, hi = l >> 5;
  const int p = blockIdx.x, h = blockIdx.y, b = blockIdx.z;
  const int kvh = h >> 2;

  const u16* Kh = Kr + ((long)(b * NKV + kvh)) * SS * HD;
  const u16* Vh = Vt + ((long)(b * NKV + kvh)) * HD * SS;
  const float scale = 0.08838834764831845f;        // 1/sqrt(128)

  auto stageK = [&](int buf, int kvb) {
    char* kb = (char*)&Ks[buf][0];
#pragma unroll
    for (int i = 0; i < 2; i++) {
      int L = w * 2048 + i * 1024 + l * 16;
      int r = L >> 8;                              // kv row 0..63
      int cl = (L >> 4) & 15;
      int cg = (cl & 8) | ((cl ^ r) & 7);
      GLOAD16((const char*)(Kh + (long)(kvb + r) * HD) + cg * 16, kb + w * 2048 + i * 1024);
    }
  };
  auto stageV = [&](int buf, int kvb) {
    char* vb = (char*)&Vs[buf][0];
#pragma unroll
    for (int i = 0; i < 2; i++) {
      int L = w * 2048 + i * 1024 + l * 16;
      int r = L >> 7;                              // d row 0..127
      int cl = (L >> 4) & 7;
      int cg = (cl ^ r) & 7;
      GLOAD16((const char*)(Vh + (long)r * SS + kvb) + cg * 16, vb + w * 2048 + i * 1024);
    }
  };

  for (int job = 0; job < 2; job++) {
    const int qt = job ? p : 7 - p;                // big job first
    const int qRow0 = qt * 256 + w * 32;
    const int qMax = qRow0 + 31;
    const int nT = 4 * qt + 4;
    const int myq = qRow0 + lq;
    const u16* Qh = Qr + (((long)(b * NH + h)) * SS + qRow0) * HD;
    u16* Yh = Y + ((long)b * SS) * DMODEL + h * HD;

    s16x8 qf[8];
#pragma unroll
    for (int kk = 0; kk < 8; kk++)
      qf[kk] = *(const s16x8*)(Qh + (long)lq * HD + kk * 16 + hi * 8);

    float m_run = -1e30f, l_run = 0.f;
    f32x16 oacc[4] = {};                           // row=crow(r,hi)=q, col=lane&31=d

    stageK(0, 0); stageV(0, 0);

    for (int t = 0; t < nT; t++) {
      const int cur = t & 1;
      if (t + 1 < nT) {
        stageK(cur ^ 1, (t + 1) * 64);
        stageV(cur ^ 1, (t + 1) * 64);
        asm volatile("s_waitcnt vmcnt(4)" ::: "memory");   // tile t landed; t+1 in flight
      } else {
        asm volatile("s_waitcnt vmcnt(0)" ::: "memory");
      }
      __builtin_amdgcn_s_barrier();
      asm volatile("" ::: "memory");

      if (t * 64 <= qMax) {
        const char* kb = (const char*)&Ks[cur][0];
        const char* vb = (const char*)&Vs[cur][0];
        f32x16 sacc[2] = {};
#pragma unroll
        for (int kk = 0; kk < 8; kk++) {
          int ch = kk * 2 + hi;
#pragma unroll
          for (int tile = 0; tile < 2; tile++) {
            int rr = tile * 32 + lq;
            int cs = (ch & 8) | ((ch ^ rr) & 7);
            s16x8 kf = *(const s16x8*)(kb + rr * 256 + cs * 16);
            sacc[tile] = __builtin_amdgcn_mfma_f32_32x32x16_bf16(kf, qf[kk], sacc[tile], 0, 0, 0);
          }
        }
        const bool full = (t * 64 + 63 <= qRow0);
        float pmax = -1e30f;
#pragma unroll
        for (int tile = 0; tile < 2; tile++)
#pragma unroll
          for (int r = 0; r < 16; r++) {
            int kv = t * 64 + tile * 32 + (r & 3) + 8 * (r >> 2) + 4 * hi;
            float v = sacc[tile][r] * scale;
            if (!full && kv > myq) v = -30000.f;
            sacc[tile][r] = v;
            pmax = fmaxf(pmax, v);
          }
        pmax = fmaxf(pmax, __shfl_xor(pmax, 32));
        if (!__all(pmax - m_run <= 8.0f)) {
          float mnew = fmaxf(m_run, pmax);
          float sf = __expf(m_run - mnew);
          m_run = mnew; l_run *= sf;
          int sfi = __builtin_bit_cast(int, sf);
#pragma unroll
          for (int r = 0; r < 16; r++) {
            int qq = (r & 3) + 8 * (r >> 2) + 4 * hi;
            float sfr = __builtin_bit_cast(float, __builtin_amdgcn_ds_bpermute(qq << 2, sfi));
#pragma unroll
            for (int n = 0; n < 4; n++) oacc[n][r] *= sfr;
          }
        }
        float rs = 0.f;
#pragma unroll
        for (int tile = 0; tile < 2; tile++)
#pragma unroll
          for (int r = 0; r < 16; r++) {
            float pv = __expf(sacc[tile][r] - m_run);
            sacc[tile][r] = pv;
            rs += pv;
          }
        rs += __shfl_xor(rs, 32);
        l_run += rs;
        s16x8 pav[4];
#pragma unroll
        for (int tile = 0; tile < 2; tile++) {
          u32 qk[8], sw[8];
#pragma unroll
          for (int j = 0; j < 8; j++) {
            qk[j] = packbf(sacc[tile][2 * j], sacc[tile][2 * j + 1]);
            sw[j] = __shfl_xor(qk[j], 32);
          }
          u32x4 f0, f1;
          f0[0] = hi ? sw[2] : qk[0];
          f0[1] = hi ? sw[3] : qk[1];
          f0[2] = hi ? qk[2] : sw[0];
          f0[3] = hi ? qk[3] : sw[1];
          f1[0] = hi ? sw[6] : qk[4];
          f1[1] = hi ? sw[7] : qk[5];
          f1[2] = hi ? qk[6] : sw[4];
          f1[3] = hi ? qk[7] : sw[5];
          pav[tile * 2 + 0] = __builtin_bit_cast(s16x8, f0);
          pav[tile * 2 + 1] = __builtin_bit_cast(s16x8, f1);
        }
#pragma unroll
        for (int n = 0; n < 4; n++) {
          int rr = n * 32 + lq;
#pragma unroll
          for (int kk = 0; kk < 4; kk++) {
            int ch = kk * 2 + hi;
            int cs = (ch ^ rr) & 7;
            s16x8 vf = *(const s16x8*)(vb + rr * 128 + cs * 16);
            oacc[n] = __builtin_amdgcn_mfma_f32_32x32x16_bf16(pav[kk], vf, oacc[n], 0, 0, 0);
          }
        }
      }
      asm volatile("" ::: "memory");
      __builtin_amdgcn_s_barrier();                // all reads done before next overwrite
      asm volatile("" ::: "memory");
    }

    float linv = 1.f / l_run;
    int li = __builtin_bit_cast(int, linv);
#pragma unroll
    for (int r = 0; r < 16; r++) {
      int qq = (r & 3) + 8 * (r >> 2) + 4 * hi;
      float lr_ = __builtin_bit_cast(float, __builtin_amdgcn_ds_bpermute(qq << 2, li));
      u16* yrow = Yh + (long)(qRow0 + qq) * DMODEL;
#pragma unroll
      for (int n = 0; n < 4; n++)
        yrow[n * 32 + lq] = f2bf(oacc[n][r] * lr_);
    }
  }
}

// ---------------------------------------------------------------- launch
extern "C" void kernel_launch(void* const* d_in, const int* in_sizes, int n_in,
                              void* d_out, int out_size, void* d_ws, size_t ws_size,
                              hipStream_t stream) {
  const float* x  = (const float*)d_in[0];
  const float* wq = (const float*)d_in[1];
  const float* wk = (const float*)d_in[2];
  const float* wv = (const float*)d_in[3];
  const float* wo = (const float*)d_in[4];
  float* out = (float*)d_out;
  char* ws = (char*)d_ws;

  u16* Xb   = (u16*)ws;                    // 33,554,432 B  (aliased as Y after qkv gemm)
  u16* Wqkv = (u16*)(ws + 33554432);       // 12,582,912 B
  u16* Wob  = (u16*)(ws + 46137344);       //  8,388,608 B
  u16* Qr   = (u16*)(ws + 54525952);       // 33,554,432 B
  u16* Kr   = (u16*)(ws + 88080384);       //  8,388,608 B
  u16* Vt   = (u16*)(ws + 96468992);       //  8,388,608 B
  u16* Y    = Xb;

  cast_all<<<26624, 256, 0, stream>>>(x, wq, wk, wv, wo, Xb, Wqkv, Wob);
  gemm256<12, 0><<<384, 512, 0, stream>>>(Xb, Wqkv, DMODEL, Qr, Kr, Vt, nullptr);
  rope_kernel<<<40960, 256, 0, stream>>>(Qr, Kr);
  dim3 ag(4, NH, NB);
  attn_fwd<<<ag, 512, 0, stream>>>(Qr, Kr, Vt, Y);
  gemm256<8, 1><<<256, 512, 0, stream>>>(Y, Wob, DMODEL, nullptr, nullptr, nullptr, out);
}